// Round 2
// baseline (456.375 us; speedup 1.0000x reference)
//
#include <hip/hip_runtime.h>
#include <hip/hip_bf16.h>
#include <math.h>

// Problem constants
#define TOKENS 131072      // 32*64*64 tokens
#define CIN    128         // input channels
#define F3     384         // 3*DIM qkv output channels
#define NTOK   4096        // tokens per batch (64*64)
#define LN_EPS 1e-5f

// NOTE: macro params must not be named x/y/z/w — member access .w would be substituted.
#define COMP(vec, rr) ((rr)==0 ? (vec).x : (rr)==1 ? (vec).y : (rr)==2 ? (vec).z : (vec).w)
#define FMA4(acc, sc, vec) { (acc).x += (sc)*(vec).x; (acc).y += (sc)*(vec).y; (acc).z += (sc)*(vec).z; (acc).w += (sc)*(vec).w; }

// ---------------------------------------------------------------------------
// K1: qkv = x @ w_qkv   ([131072,128] x [128,384])
// grid 1024 blocks x 512 thr; tile 128 tokens x 128 f (3 f-chunks), K=128.
// Per thread: 4 tokens x 8 f (two float4 quads at 4g and 64+4g -> LDS reads
// conflict-free: 16 lanes x stride-4-words = 2 words/bank = free).
// Dynamic LDS: x[128][132] (pad 132: token rows 4 apart land 16 banks apart)
// + w[128][128] = 133120 B.
// ---------------------------------------------------------------------------
__global__ __launch_bounds__(512, 2) void k_qkv(
    const float* __restrict__ x, const float* __restrict__ w, float* __restrict__ qkv)
{
    extern __shared__ float smem[];
    float (*xs)[132] = reinterpret_cast<float (*)[132]>(smem);
    float (*wl)[128] = reinterpret_cast<float (*)[128]>(smem + 128 * 132);

    const int t = threadIdx.x;
    const long row0 = (long)blockIdx.x * 128;

    // stage x tile: 128 rows x 32 float4
#pragma unroll
    for (int r = 0; r < 8; ++r) {
        int j = t + 512 * r;
        int rr = j >> 5, c4 = j & 31;
        float4 v = reinterpret_cast<const float4*>(x + (row0 + rr) * CIN)[c4];
        *reinterpret_cast<float4*>(&xs[rr][c4 * 4]) = v;
    }

    const int g   = t & 15;
    const int tg  = t >> 4;          // 0..31
    const int tok0 = tg * 4;
    const int fA = g * 4;
    const int fB = 64 + g * 4;

    for (int fc = 0; fc < 3; ++fc) {
        __syncthreads();
        // stage w chunk [128 k][128 f]
#pragma unroll
        for (int r = 0; r < 8; ++r) {
            int j = t + 512 * r;
            int kr = j >> 5, c4 = j & 31;
            float4 v = reinterpret_cast<const float4*>(w + (size_t)kr * F3 + fc * 128)[c4];
            *reinterpret_cast<float4*>(&wl[kr][c4 * 4]) = v;
        }
        __syncthreads();

        float4 accA[4], accB[4];
#pragma unroll
        for (int i = 0; i < 4; ++i) {
            accA[i] = make_float4(0.f, 0.f, 0.f, 0.f);
            accB[i] = make_float4(0.f, 0.f, 0.f, 0.f);
        }
#pragma unroll 2
        for (int kk = 0; kk < 128; kk += 4) {
            float4 xa[4];
#pragma unroll
            for (int i = 0; i < 4; ++i)
                xa[i] = *reinterpret_cast<const float4*>(&xs[tok0 + i][kk]);
#pragma unroll
            for (int r = 0; r < 4; ++r) {
                float4 wva = *reinterpret_cast<const float4*>(&wl[kk + r][fA]);
                float4 wvb = *reinterpret_cast<const float4*>(&wl[kk + r][fB]);
#pragma unroll
                for (int i = 0; i < 4; ++i) {
                    float s = COMP(xa[i], r);
                    FMA4(accA[i], s, wva);
                    FMA4(accB[i], s, wvb);
                }
            }
        }
#pragma unroll
        for (int i = 0; i < 4; ++i) {
            float* dst = qkv + (row0 + tok0 + i) * (long)F3 + fc * 128;
            *reinterpret_cast<float4*>(dst + fA) = accA[i];
            *reinterpret_cast<float4*>(dst + fB) = accB[i];
        }
    }
}

// ---------------------------------------------------------------------------
// K2: ctx_raw[b,h,d,e] = sum_n exp(k[b,n,h,d]) * v[b,n,h,e]
//     ksum[b,h,d]      = sum_n exp(k[b,n,h,d])
// k values ~N(0,1): exp() safe in fp32 without max subtraction (identical math
// to softmax-with-max). grid (16 n-chunks, 128 bh), 256 thr; chunk = 256 tok.
// Partial sums accumulated via atomicAdd into zeroed ws.
// ---------------------------------------------------------------------------
__global__ __launch_bounds__(256, 4) void k_ctx(
    const float* __restrict__ qkv, float* __restrict__ ctx_raw, float* __restrict__ ksum)
{
    __shared__ float ek[64][33];   // pad 33: read ek[n][d] conflict-free, scalar writes spread
    __shared__ float vs[64][32];

    const int t = threadIdx.x;
    const int bh = blockIdx.y;
    const int b = bh >> 2, h = bh & 3;
    const long rowbase = (long)b * NTOK + blockIdx.x * 256;

    const int d  = t & 31;
    const int e0 = (t >> 5) * 4;   // 8 groups x 4 e

    float4 acc = make_float4(0.f, 0.f, 0.f, 0.f);
    float suml = 0.f;

    for (int tile = 0; tile < 4; ++tile) {
        __syncthreads();
#pragma unroll
        for (int r = 0; r < 2; ++r) {
            int j = t + 256 * r;          // 0..511
            int tok = j >> 3, c4 = j & 7;
            const float* rowp = qkv + (rowbase + tile * 64 + tok) * (long)F3 + h * 32 + c4 * 4;
            float4 kv = *reinterpret_cast<const float4*>(rowp + 128);   // k slice
            ek[tok][c4 * 4 + 0] = __expf(kv.x);
            ek[tok][c4 * 4 + 1] = __expf(kv.y);
            ek[tok][c4 * 4 + 2] = __expf(kv.z);
            ek[tok][c4 * 4 + 3] = __expf(kv.w);
            float4 vv = *reinterpret_cast<const float4*>(rowp + 256);   // v slice
            *reinterpret_cast<float4*>(&vs[tok][c4 * 4]) = vv;
        }
        __syncthreads();
#pragma unroll 8
        for (int n = 0; n < 64; ++n) {
            float e = ek[n][d];
            float4 vv = *reinterpret_cast<const float4*>(&vs[n][e0]);
            FMA4(acc, e, vv);
            suml += e;
        }
    }

    float* cp = ctx_raw + (size_t)bh * 1024 + d * 32 + e0;
    atomicAdd(cp + 0, acc.x);
    atomicAdd(cp + 1, acc.y);
    atomicAdd(cp + 2, acc.z);
    atomicAdd(cp + 3, acc.w);
    if (t < 32) atomicAdd(ksum + bh * 32 + d, suml);   // 8 e-groups computed identical suml; write once
}

// ---------------------------------------------------------------------------
// K3: per 64 tokens: q-softmax -> out = ctx_norm . q -> @ w_out + b -> LN.
// 256 thr: g = t&15 owns channel quads {4g, 64+4g}; tg = t>>4 owns tokens tg*4+i.
// ql rows permuted (rowp = i*16+tg) so simultaneous reads are 2-way/bank (free).
// All scales folded: ctx_norm = ctx_raw/(ksum*N); q scaled by 1/(sum*sqrt(32)).
// LDS = ctx 16K + ql[64][132] 33K + wl[16][128] 8K = 58368 B -> 2 blocks/CU.
// ---------------------------------------------------------------------------
__global__ __launch_bounds__(256, 2) void k_out(
    const float* __restrict__ qkv, const float* __restrict__ ctx_raw, const float* __restrict__ ksum,
    const float* __restrict__ w_out, const float* __restrict__ b_out, const float* __restrict__ ln_scale,
    float* __restrict__ out)
{
    __shared__ float ctx[4 * 32 * 32];
    __shared__ float ql[64][132];
    __shared__ float wl[16][128];

    const int t = threadIdx.x;
    const long row0 = (long)blockIdx.x * 64;
    const int b = (int)(row0 >> 12);

    // phase 1: normalized context into LDS
#pragma unroll
    for (int r = 0; r < 16; ++r) {
        int j = t + 256 * r;
        float ks = ksum[b * 128 + (j >> 5)];
        ctx[j] = ctx_raw[(size_t)b * 4096 + j] / (ks * 4096.0f);
    }

    const int g  = t & 15;
    const int tg = t >> 4;             // 0..15
    const int cA = g * 4;
    const int cB = 64 + g * 4;
    const int hA = g >> 3;             // head of A-quad: 0/1
    const int hB = hA + 2;             // head of B-quad: 2/3
    const int eA = cA & 31;            // e-offset within head (same for A and B)

    // phase 2: load q, softmax over each head's 32 dims (octet shuffle reduce)
#pragma unroll
    for (int i = 0; i < 4; ++i) {
        long row = row0 + tg * 4 + i;
        const float* qp = qkv + row * (long)F3;
        float4 a = *reinterpret_cast<const float4*>(qp + cA);
        float4 c = *reinterpret_cast<const float4*>(qp + cB);
        float mA = fmaxf(fmaxf(a.x, a.y), fmaxf(a.z, a.w));
        float mB = fmaxf(fmaxf(c.x, c.y), fmaxf(c.z, c.w));
        mA = fmaxf(mA, __shfl_xor(mA, 1)); mA = fmaxf(mA, __shfl_xor(mA, 2)); mA = fmaxf(mA, __shfl_xor(mA, 4));
        mB = fmaxf(mB, __shfl_xor(mB, 1)); mB = fmaxf(mB, __shfl_xor(mB, 2)); mB = fmaxf(mB, __shfl_xor(mB, 4));
        a.x = __expf(a.x - mA); a.y = __expf(a.y - mA); a.z = __expf(a.z - mA); a.w = __expf(a.w - mA);
        c.x = __expf(c.x - mB); c.y = __expf(c.y - mB); c.z = __expf(c.z - mB); c.w = __expf(c.w - mB);
        float sA = a.x + a.y + a.z + a.w;
        float sB = c.x + c.y + c.z + c.w;
        sA += __shfl_xor(sA, 1); sA += __shfl_xor(sA, 2); sA += __shfl_xor(sA, 4);
        sB += __shfl_xor(sB, 1); sB += __shfl_xor(sB, 2); sB += __shfl_xor(sB, 4);
        float rA = 1.0f / (sA * 5.65685424949238f);   // includes 1/sqrt(32)
        float rB = 1.0f / (sB * 5.65685424949238f);
        a.x *= rA; a.y *= rA; a.z *= rA; a.w *= rA;
        c.x *= rB; c.y *= rB; c.z *= rB; c.w *= rB;
        int rowp = (i << 4) + tg;
        *reinterpret_cast<float4*>(&ql[rowp][cA]) = a;
        *reinterpret_cast<float4*>(&ql[rowp][cB]) = c;
    }
    __syncthreads();

    // phase 3: out_tok[h*32+e] = sum_d ctx[h][d][e] * q_sm[h*32+d]
    float4 yA[4], yB[4];
#pragma unroll
    for (int i = 0; i < 4; ++i) {
        yA[i] = make_float4(0.f, 0.f, 0.f, 0.f);
        yB[i] = make_float4(0.f, 0.f, 0.f, 0.f);
    }
#pragma unroll
    for (int dd = 0; dd < 32; dd += 4) {
        float4 qfA[4], qfB[4];
#pragma unroll
        for (int i = 0; i < 4; ++i) {
            int rowp = (i << 4) + tg;
            qfA[i] = *reinterpret_cast<const float4*>(&ql[rowp][hA * 32 + dd]);
            qfB[i] = *reinterpret_cast<const float4*>(&ql[rowp][hB * 32 + dd]);
        }
#pragma unroll
        for (int r = 0; r < 4; ++r) {
            float4 ca = *reinterpret_cast<const float4*>(&ctx[hA * 1024 + (dd + r) * 32 + eA]);
            float4 cb = *reinterpret_cast<const float4*>(&ctx[hB * 1024 + (dd + r) * 32 + eA]);
#pragma unroll
            for (int i = 0; i < 4; ++i) {
                float sa = COMP(qfA[i], r);
                float sb = COMP(qfB[i], r);
                FMA4(yA[i], sa, ca);
                FMA4(yB[i], sb, cb);
            }
        }
    }
    __syncthreads();

    // phase 4: stash out-tokens into ql (q fully consumed)
#pragma unroll
    for (int i = 0; i < 4; ++i) {
        int rowp = (i << 4) + tg;
        *reinterpret_cast<float4*>(&ql[rowp][cA]) = yA[i];
        *reinterpret_cast<float4*>(&ql[rowp][cB]) = yB[i];
    }

    // phase 5: y = ot @ w_out + b_out  (K=128 in 8 chunks of 16 rows)
    float4 b4a = *reinterpret_cast<const float4*>(b_out + cA);
    float4 b4b = *reinterpret_cast<const float4*>(b_out + cB);
    float4 zA[4], zB[4];
#pragma unroll
    for (int i = 0; i < 4; ++i) { zA[i] = b4a; zB[i] = b4b; }

    for (int dc = 0; dc < 8; ++dc) {
        __syncthreads();
#pragma unroll
        for (int r = 0; r < 2; ++r) {
            int j = t + 256 * r;          // 0..511
            int rr = j >> 5, c4 = j & 31; // 16 rows x 32 float4
            *reinterpret_cast<float4*>(&wl[rr][c4 * 4]) =
                *reinterpret_cast<const float4*>(w_out + (size_t)(dc * 16 + rr) * 128 + c4 * 4);
        }
        __syncthreads();
#pragma unroll
        for (int dd = 0; dd < 16; dd += 4) {
            float4 ot[4];
#pragma unroll
            for (int i = 0; i < 4; ++i) {
                int rowp = (i << 4) + tg;
                ot[i] = *reinterpret_cast<const float4*>(&ql[rowp][dc * 16 + dd]);
            }
#pragma unroll
            for (int r = 0; r < 4; ++r) {
                float4 wva = *reinterpret_cast<const float4*>(&wl[dd + r][cA]);
                float4 wvb = *reinterpret_cast<const float4*>(&wl[dd + r][cB]);
#pragma unroll
                for (int i = 0; i < 4; ++i) {
                    float s = COMP(ot[i], r);
                    FMA4(zA[i], s, wva);
                    FMA4(zB[i], s, wvb);
                }
            }
        }
    }

    // phase 6: LayerNorm over 128 channels (16-lane shuffle reduce) + store
    float4 ln4a = *reinterpret_cast<const float4*>(ln_scale + cA);
    float4 ln4b = *reinterpret_cast<const float4*>(ln_scale + cB);
#pragma unroll
    for (int i = 0; i < 4; ++i) {
        float s1 = zA[i].x + zA[i].y + zA[i].z + zA[i].w + zB[i].x + zB[i].y + zB[i].z + zB[i].w;
        float s2 = zA[i].x * zA[i].x + zA[i].y * zA[i].y + zA[i].z * zA[i].z + zA[i].w * zA[i].w
                 + zB[i].x * zB[i].x + zB[i].y * zB[i].y + zB[i].z * zB[i].z + zB[i].w * zB[i].w;
        s1 += __shfl_xor(s1, 1); s1 += __shfl_xor(s1, 2); s1 += __shfl_xor(s1, 4); s1 += __shfl_xor(s1, 8);
        s2 += __shfl_xor(s2, 1); s2 += __shfl_xor(s2, 2); s2 += __shfl_xor(s2, 4); s2 += __shfl_xor(s2, 8);
        float mu  = s1 * (1.0f / 128.0f);
        float var = s2 * (1.0f / 128.0f) - mu * mu;
        float sc  = rsqrtf(var + LN_EPS);
        float4 oA, oB;
        oA.x = (zA[i].x - mu) * sc * ln4a.x; oA.y = (zA[i].y - mu) * sc * ln4a.y;
        oA.z = (zA[i].z - mu) * sc * ln4a.z; oA.w = (zA[i].w - mu) * sc * ln4a.w;
        oB.x = (zB[i].x - mu) * sc * ln4b.x; oB.y = (zB[i].y - mu) * sc * ln4b.y;
        oB.z = (zB[i].z - mu) * sc * ln4b.z; oB.w = (zB[i].w - mu) * sc * ln4b.w;
        long row = row0 + tg * 4 + i;
        *reinterpret_cast<float4*>(out + row * 128 + cA) = oA;
        *reinterpret_cast<float4*>(out + row * 128 + cB) = oB;
    }
}

// ---------------------------------------------------------------------------
extern "C" void kernel_launch(void* const* d_in, const int* in_sizes, int n_in,
                              void* d_out, int out_size, void* d_ws, size_t ws_size,
                              hipStream_t stream) {
    const float* x        = (const float*)d_in[0];
    const float* w_qkv    = (const float*)d_in[1];
    const float* w_out    = (const float*)d_in[2];
    const float* b_out    = (const float*)d_in[3];
    const float* ln_scale = (const float*)d_in[4];
    float* out = (float*)d_out;

    float* qkv     = (float*)d_ws;                      // [131072][384] fp32
    size_t qkv_el  = (size_t)TOKENS * F3;
    float* ctx_raw = qkv + qkv_el;                      // [32*4][32*32]
    float* ksum    = ctx_raw + 131072;                  // [32*4][32]
    size_t need = (qkv_el + 131072 + 4096) * sizeof(float);
    if (ws_size < need) return;  // ws too small -> clean validation failure, not a fault

    (void)hipMemsetAsync(ctx_raw, 0, (131072 + 4096) * sizeof(float), stream);

    const int k1_lds = (128 * 132 + 128 * 128) * sizeof(float);  // 133120 B
    (void)hipFuncSetAttribute(reinterpret_cast<const void*>(k_qkv),
                              hipFuncAttributeMaxDynamicSharedMemorySize, k1_lds);
    hipLaunchKernelGGL(k_qkv, dim3(1024), dim3(512), k1_lds, stream, x, w_qkv, qkv);
    hipLaunchKernelGGL(k_ctx, dim3(16, 128), dim3(256), 0, stream, qkv, ctx_raw, ksum);
    hipLaunchKernelGGL(k_out, dim3(2048), dim3(256), 0, stream, qkv, ctx_raw, ksum,
                       w_out, b_out, ln_scale, out);
}

// Round 3
// 307.613 us; speedup vs baseline: 1.4836x; 1.4836x over previous
//
#include <hip/hip_runtime.h>
#include <hip/hip_bf16.h>
#include <math.h>

// Problem constants
#define TOKENS 131072      // 32*64*64 tokens
#define CIN    128         // input channels
#define F3     384         // 3*DIM qkv output channels
#define NTOK   4096        // tokens per batch (64*64)
#define LN_EPS 1e-5f

typedef unsigned short u16;
typedef u16   u16x4 __attribute__((ext_vector_type(4)));
typedef u16   u16x8 __attribute__((ext_vector_type(8)));
typedef __bf16 bf16x8 __attribute__((ext_vector_type(8)));
typedef float f32x4  __attribute__((ext_vector_type(4)));

// NOTE: macro params must not be named x/y/z/w — member access .w would be substituted.
#define COMP(vec, rr) ((rr)==0 ? (vec).x : (rr)==1 ? (vec).y : (rr)==2 ? (vec).z : (vec).w)
#define FMA4(acc, sc, vec) { (acc).x += (sc)*(vec).x; (acc).y += (sc)*(vec).y; (acc).z += (sc)*(vec).z; (acc).w += (sc)*(vec).w; }

static __device__ __forceinline__ u16 f2b(float f) {
    __bf16 h = (__bf16)f;                      // RNE hardware convert
    union { __bf16 hh; u16 uu; } c; c.hh = h; return c.uu;
}
static __device__ __forceinline__ float b2f(u16 u) {
    return __uint_as_float(((unsigned)u) << 16);
}

// LDS XOR swizzle for [128 rows][128 bf16] tiles read as ds_read_b128 down rows
// (T2, §6 G4). Element-index form of byte ^= ((row&7)<<4).
#define SWZ(rr, cc) ((((rr) * 128) + (cc)) ^ (((rr) & 7) << 3))

// ---------------------------------------------------------------------------
// K0: wT[f][k] = bf16(w_qkv[k][f])   (tiny: 384x128)
// ---------------------------------------------------------------------------
__global__ void k_prep_w(const float* __restrict__ w, u16* __restrict__ wT) {
    int t = blockIdx.x * 256 + threadIdx.x;
    if (t < F3 * CIN) {
        int f = t >> 7, k = t & 127;
        wT[t] = f2b(w[(size_t)k * F3 + f]);    // coalesced write, strided read (L2)
    }
}

// ---------------------------------------------------------------------------
// K1: qkv = bf16( x @ w_qkv )  via mfma_f32_16x16x32_bf16.
// Tile 128 tok x 128 f, K=128 single pass. 256 thr = 4 waves (2x2), each wave
// owns a 64x64 sub-tile = 4x4 fragments. A (x, converted f32->bf16 in-stage)
// and B (wT, pre-converted) both live in swizzled LDS (conflict-free b128).
// grid = 1024 m-tiles x 3 f-chunks, fc fastest (x tile L2-reuse).
// ---------------------------------------------------------------------------
__global__ __launch_bounds__(256, 2) void k_qkv(
    const float* __restrict__ x, const u16* __restrict__ wT, u16* __restrict__ qkv)
{
    extern __shared__ u16 lds[];
    u16* As = lds;            // 128x128 bf16, swizzled
    u16* Bs = lds + 16384;    // 128x128 bf16 (rows = f, cols = k), swizzled

    const int t  = threadIdx.x;
    const int fc = blockIdx.x % 3;
    const long row0 = (long)(blockIdx.x / 3) * 128;

    // stage A: 128 rows x 32 float4, convert to bf16, swizzled 8B writes
#pragma unroll
    for (int i = 0; i < 16; ++i) {
        int idx = i * 256 + t;
        int r = idx >> 5, c4 = idx & 31;
        float4 v = reinterpret_cast<const float4*>(x + (row0 + r) * CIN)[c4];
        u16x4 b; b.x = f2b(v.x); b.y = f2b(v.y); b.z = f2b(v.z); b.w = f2b(v.w);
        *reinterpret_cast<u16x4*>(&As[SWZ(r, c4 * 4)]) = b;
    }
    // stage B: 128 f-rows x 16 u16x8 units, swizzled 16B writes
#pragma unroll
    for (int i = 0; i < 8; ++i) {
        int idx = i * 256 + t;
        int f = idx >> 4, u = idx & 15;
        u16x8 wv = *reinterpret_cast<const u16x8*>(wT + (size_t)(fc * 128 + f) * 128 + u * 8);
        *reinterpret_cast<u16x8*>(&Bs[SWZ(f, u * 8)]) = wv;
    }
    __syncthreads();

    const int lane = t & 63, wid = t >> 6;
    const int wm = (wid >> 1) * 64, wn = (wid & 1) * 64;
    const int lr = lane & 15, lk = lane >> 4;

    f32x4 acc[4][4];
#pragma unroll
    for (int mi = 0; mi < 4; ++mi)
#pragma unroll
        for (int ni = 0; ni < 4; ++ni)
            acc[mi][ni] = (f32x4){0.f, 0.f, 0.f, 0.f};

#pragma unroll
    for (int ks = 0; ks < 4; ++ks) {
        bf16x8 a[4], b[4];
        const int kc = ks * 32 + lk * 8;
#pragma unroll
        for (int mi = 0; mi < 4; ++mi)
            a[mi] = *reinterpret_cast<const bf16x8*>(&As[SWZ(wm + mi * 16 + lr, kc)]);
#pragma unroll
        for (int ni = 0; ni < 4; ++ni)
            b[ni] = *reinterpret_cast<const bf16x8*>(&Bs[SWZ(wn + ni * 16 + lr, kc)]);
#pragma unroll
        for (int mi = 0; mi < 4; ++mi)
#pragma unroll
            for (int ni = 0; ni < 4; ++ni)
                acc[mi][ni] = __builtin_amdgcn_mfma_f32_16x16x32_bf16(a[mi], b[ni], acc[mi][ni], 0, 0, 0);
    }

    // C write: row=(lane>>4)*4+reg, col=lane&15 (m89-verified layout)
#pragma unroll
    for (int mi = 0; mi < 4; ++mi) {
#pragma unroll
        for (int ni = 0; ni < 4; ++ni) {
            const int col = fc * 128 + wn + ni * 16 + lr;
            const long rbase = row0 + wm + mi * 16 + lk * 4;
#pragma unroll
            for (int r = 0; r < 4; ++r)
                qkv[(rbase + r) * F3 + col] = f2b(acc[mi][ni][r]);
        }
    }
}

// ---------------------------------------------------------------------------
// K2: ctx_raw[b,h,d,e] = sum_n exp(k[b,n,h,d]) * v[b,n,h,e]; ksum likewise.
// qkv now bf16. grid (16 n-chunks, 128 bh), 256 thr; atomics into zeroed ws.
// ---------------------------------------------------------------------------
__global__ __launch_bounds__(256, 4) void k_ctx(
    const u16* __restrict__ qkv, float* __restrict__ ctx_raw, float* __restrict__ ksum)
{
    __shared__ float ek[64][33];
    __shared__ float vs[64][32];

    const int t = threadIdx.x;
    const int bh = blockIdx.y;
    const int b = bh >> 2, h = bh & 3;
    const long rowbase = (long)b * NTOK + blockIdx.x * 256;

    const int d  = t & 31;
    const int e0 = (t >> 5) * 4;

    float4 acc = make_float4(0.f, 0.f, 0.f, 0.f);
    float suml = 0.f;

    for (int tile = 0; tile < 4; ++tile) {
        __syncthreads();
#pragma unroll
        for (int r = 0; r < 2; ++r) {
            int j = t + 256 * r;
            int tok = j >> 3, c4 = j & 7;
            const u16* rowp = qkv + (rowbase + tile * 64 + tok) * (long)F3 + h * 32 + c4 * 4;
            u16x4 kv = *reinterpret_cast<const u16x4*>(rowp + 128);
            ek[tok][c4 * 4 + 0] = __expf(b2f(kv.x));
            ek[tok][c4 * 4 + 1] = __expf(b2f(kv.y));
            ek[tok][c4 * 4 + 2] = __expf(b2f(kv.z));
            ek[tok][c4 * 4 + 3] = __expf(b2f(kv.w));
            u16x4 vv = *reinterpret_cast<const u16x4*>(rowp + 256);
            float4 vf = make_float4(b2f(vv.x), b2f(vv.y), b2f(vv.z), b2f(vv.w));
            *reinterpret_cast<float4*>(&vs[tok][c4 * 4]) = vf;
        }
        __syncthreads();
#pragma unroll 8
        for (int n = 0; n < 64; ++n) {
            float e = ek[n][d];
            float4 vv = *reinterpret_cast<const float4*>(&vs[n][e0]);
            FMA4(acc, e, vv);
            suml += e;
        }
    }

    float* cp = ctx_raw + (size_t)bh * 1024 + d * 32 + e0;
    atomicAdd(cp + 0, acc.x);
    atomicAdd(cp + 1, acc.y);
    atomicAdd(cp + 2, acc.z);
    atomicAdd(cp + 3, acc.w);
    if (t < 32) atomicAdd(ksum + bh * 32 + d, suml);
}

// ---------------------------------------------------------------------------
// K3: per 64 tokens: q-softmax -> ctx.q -> @w_out + b -> LN. qkv now bf16.
// ---------------------------------------------------------------------------
__global__ __launch_bounds__(256, 2) void k_out(
    const u16* __restrict__ qkv, const float* __restrict__ ctx_raw, const float* __restrict__ ksum,
    const float* __restrict__ w_out, const float* __restrict__ b_out, const float* __restrict__ ln_scale,
    float* __restrict__ out)
{
    __shared__ float ctx[4 * 32 * 32];
    __shared__ float ql[64][132];
    __shared__ float wl[16][128];

    const int t = threadIdx.x;
    const long row0 = (long)blockIdx.x * 64;
    const int b = (int)(row0 >> 12);

    // phase 1: normalized context into LDS
#pragma unroll
    for (int r = 0; r < 16; ++r) {
        int j = t + 256 * r;
        float ks = ksum[b * 128 + (j >> 5)];
        ctx[j] = ctx_raw[(size_t)b * 4096 + j] / (ks * 4096.0f);
    }

    const int g  = t & 15;
    const int tg = t >> 4;
    const int cA = g * 4;
    const int cB = 64 + g * 4;
    const int hA = g >> 3;
    const int hB = hA + 2;
    const int eA = cA & 31;

    // phase 2: q softmax (per-head 32 dims, octet shuffle reduce)
#pragma unroll
    for (int i = 0; i < 4; ++i) {
        long row = row0 + tg * 4 + i;
        const u16* qp = qkv + row * (long)F3;
        u16x4 av = *reinterpret_cast<const u16x4*>(qp + cA);
        u16x4 cv = *reinterpret_cast<const u16x4*>(qp + cB);
        float4 a = make_float4(b2f(av.x), b2f(av.y), b2f(av.z), b2f(av.w));
        float4 c = make_float4(b2f(cv.x), b2f(cv.y), b2f(cv.z), b2f(cv.w));
        float mA = fmaxf(fmaxf(a.x, a.y), fmaxf(a.z, a.w));
        float mB = fmaxf(fmaxf(c.x, c.y), fmaxf(c.z, c.w));
        mA = fmaxf(mA, __shfl_xor(mA, 1)); mA = fmaxf(mA, __shfl_xor(mA, 2)); mA = fmaxf(mA, __shfl_xor(mA, 4));
        mB = fmaxf(mB, __shfl_xor(mB, 1)); mB = fmaxf(mB, __shfl_xor(mB, 2)); mB = fmaxf(mB, __shfl_xor(mB, 4));
        a.x = __expf(a.x - mA); a.y = __expf(a.y - mA); a.z = __expf(a.z - mA); a.w = __expf(a.w - mA);
        c.x = __expf(c.x - mB); c.y = __expf(c.y - mB); c.z = __expf(c.z - mB); c.w = __expf(c.w - mB);
        float sA = a.x + a.y + a.z + a.w;
        float sB = c.x + c.y + c.z + c.w;
        sA += __shfl_xor(sA, 1); sA += __shfl_xor(sA, 2); sA += __shfl_xor(sA, 4);
        sB += __shfl_xor(sB, 1); sB += __shfl_xor(sB, 2); sB += __shfl_xor(sB, 4);
        float rA = 1.0f / (sA * 5.65685424949238f);
        float rB = 1.0f / (sB * 5.65685424949238f);
        a.x *= rA; a.y *= rA; a.z *= rA; a.w *= rA;
        c.x *= rB; c.y *= rB; c.z *= rB; c.w *= rB;
        int rowp = (i << 4) + tg;
        *reinterpret_cast<float4*>(&ql[rowp][cA]) = a;
        *reinterpret_cast<float4*>(&ql[rowp][cB]) = c;
    }
    __syncthreads();

    // phase 3: out_tok[h*32+e] = sum_d ctx[h][d][e] * q_sm[h*32+d]
    float4 yA[4], yB[4];
#pragma unroll
    for (int i = 0; i < 4; ++i) {
        yA[i] = make_float4(0.f, 0.f, 0.f, 0.f);
        yB[i] = make_float4(0.f, 0.f, 0.f, 0.f);
    }
#pragma unroll
    for (int dd = 0; dd < 32; dd += 4) {
        float4 qfA[4], qfB[4];
#pragma unroll
        for (int i = 0; i < 4; ++i) {
            int rowp = (i << 4) + tg;
            qfA[i] = *reinterpret_cast<const float4*>(&ql[rowp][hA * 32 + dd]);
            qfB[i] = *reinterpret_cast<const float4*>(&ql[rowp][hB * 32 + dd]);
        }
#pragma unroll
        for (int r = 0; r < 4; ++r) {
            float4 ca = *reinterpret_cast<const float4*>(&ctx[hA * 1024 + (dd + r) * 32 + eA]);
            float4 cb = *reinterpret_cast<const float4*>(&ctx[hB * 1024 + (dd + r) * 32 + eA]);
#pragma unroll
            for (int i = 0; i < 4; ++i) {
                float sa = COMP(qfA[i], r);
                float sb = COMP(qfB[i], r);
                FMA4(yA[i], sa, ca);
                FMA4(yB[i], sb, cb);
            }
        }
    }
    __syncthreads();

    // phase 4: stash out-tokens into ql
#pragma unroll
    for (int i = 0; i < 4; ++i) {
        int rowp = (i << 4) + tg;
        *reinterpret_cast<float4*>(&ql[rowp][cA]) = yA[i];
        *reinterpret_cast<float4*>(&ql[rowp][cB]) = yB[i];
    }

    // phase 5: y = ot @ w_out + b_out
    float4 b4a = *reinterpret_cast<const float4*>(b_out + cA);
    float4 b4b = *reinterpret_cast<const float4*>(b_out + cB);
    float4 zA[4], zB[4];
#pragma unroll
    for (int i = 0; i < 4; ++i) { zA[i] = b4a; zB[i] = b4b; }

    for (int dc = 0; dc < 8; ++dc) {
        __syncthreads();
#pragma unroll
        for (int r = 0; r < 2; ++r) {
            int j = t + 256 * r;
            int rr = j >> 5, c4 = j & 31;
            *reinterpret_cast<float4*>(&wl[rr][c4 * 4]) =
                *reinterpret_cast<const float4*>(w_out + (size_t)(dc * 16 + rr) * 128 + c4 * 4);
        }
        __syncthreads();
#pragma unroll
        for (int dd = 0; dd < 16; dd += 4) {
            float4 ot[4];
#pragma unroll
            for (int i = 0; i < 4; ++i) {
                int rowp = (i << 4) + tg;
                ot[i] = *reinterpret_cast<const float4*>(&ql[rowp][dc * 16 + dd]);
            }
#pragma unroll
            for (int r = 0; r < 4; ++r) {
                float4 wva = *reinterpret_cast<const float4*>(&wl[dd + r][cA]);
                float4 wvb = *reinterpret_cast<const float4*>(&wl[dd + r][cB]);
#pragma unroll
                for (int i = 0; i < 4; ++i) {
                    float s = COMP(ot[i], r);
                    FMA4(zA[i], s, wva);
                    FMA4(zB[i], s, wvb);
                }
            }
        }
    }

    // phase 6: LayerNorm + store
    float4 ln4a = *reinterpret_cast<const float4*>(ln_scale + cA);
    float4 ln4b = *reinterpret_cast<const float4*>(ln_scale + cB);
#pragma unroll
    for (int i = 0; i < 4; ++i) {
        float s1 = zA[i].x + zA[i].y + zA[i].z + zA[i].w + zB[i].x + zB[i].y + zB[i].z + zB[i].w;
        float s2 = zA[i].x * zA[i].x + zA[i].y * zA[i].y + zA[i].z * zA[i].z + zA[i].w * zA[i].w
                 + zB[i].x * zB[i].x + zB[i].y * zB[i].y + zB[i].z * zB[i].z + zB[i].w * zB[i].w;
        s1 += __shfl_xor(s1, 1); s1 += __shfl_xor(s1, 2); s1 += __shfl_xor(s1, 4); s1 += __shfl_xor(s1, 8);
        s2 += __shfl_xor(s2, 1); s2 += __shfl_xor(s2, 2); s2 += __shfl_xor(s2, 4); s2 += __shfl_xor(s2, 8);
        float mu  = s1 * (1.0f / 128.0f);
        float var = s2 * (1.0f / 128.0f) - mu * mu;
        float sc  = rsqrtf(var + LN_EPS);
        float4 oA, oB;
        oA.x = (zA[i].x - mu) * sc * ln4a.x; oA.y = (zA[i].y - mu) * sc * ln4a.y;
        oA.z = (zA[i].z - mu) * sc * ln4a.z; oA.w = (zA[i].w - mu) * sc * ln4a.w;
        oB.x = (zB[i].x - mu) * sc * ln4b.x; oB.y = (zB[i].y - mu) * sc * ln4b.y;
        oB.z = (zB[i].z - mu) * sc * ln4b.z; oB.w = (zB[i].w - mu) * sc * ln4b.w;
        long row = row0 + tg * 4 + i;
        *reinterpret_cast<float4*>(out + row * 128 + cA) = oA;
        *reinterpret_cast<float4*>(out + row * 128 + cB) = oB;
    }
}

// ---------------------------------------------------------------------------
extern "C" void kernel_launch(void* const* d_in, const int* in_sizes, int n_in,
                              void* d_out, int out_size, void* d_ws, size_t ws_size,
                              hipStream_t stream) {
    const float* x        = (const float*)d_in[0];
    const float* w_qkv    = (const float*)d_in[1];
    const float* w_out    = (const float*)d_in[2];
    const float* b_out    = (const float*)d_in[3];
    const float* ln_scale = (const float*)d_in[4];
    float* out = (float*)d_out;

    u16*   qkv     = (u16*)d_ws;                        // [131072][384] bf16
    size_t qkv_el  = (size_t)TOKENS * F3;
    u16*   wT      = qkv + qkv_el;                      // [384][128] bf16
    float* ctx_raw = (float*)(wT + (size_t)F3 * CIN);   // [128][1024] f32
    float* ksum    = ctx_raw + 131072;                  // [128][32]   f32
    size_t need = qkv_el * 2 + (size_t)F3 * CIN * 2 + (131072 + 4096) * sizeof(float);
    if (ws_size < need) return;

    (void)hipMemsetAsync(ctx_raw, 0, (131072 + 4096) * sizeof(float), stream);

    const int k1_lds = 2 * 16384 * sizeof(u16);         // 65536 B
    (void)hipFuncSetAttribute(reinterpret_cast<const void*>(k_qkv),
                              hipFuncAttributeMaxDynamicSharedMemorySize, k1_lds);
    hipLaunchKernelGGL(k_prep_w, dim3(192), dim3(256), 0, stream, w_qkv, wT);
    hipLaunchKernelGGL(k_qkv, dim3(3072), dim3(256), k1_lds, stream, x, wT, qkv);
    hipLaunchKernelGGL(k_ctx, dim3(16, 128), dim3(256), 0, stream, qkv, ctx_raw, ksum);
    hipLaunchKernelGGL(k_out, dim3(2048), dim3(256), 0, stream, qkv, ctx_raw, ksum,
                       w_out, b_out, ln_scale, out);
}

// Round 6
// 203.223 us; speedup vs baseline: 2.2457x; 1.5137x over previous
//
#include <hip/hip_runtime.h>
#include <hip/hip_bf16.h>
#include <math.h>

// Problem constants
#define TOKENS 131072      // 32*64*64 tokens
#define CIN    128         // input channels
#define F3     384         // 3*DIM qkv output channels
#define NTOK   4096        // tokens per batch (64*64)
#define LN_EPS 1e-5f

typedef unsigned short u16;
typedef u16   u16x4 __attribute__((ext_vector_type(4)));
typedef u16   u16x8 __attribute__((ext_vector_type(8)));
typedef __bf16 bf16x8 __attribute__((ext_vector_type(8)));
typedef float f32x4  __attribute__((ext_vector_type(4)));

static __device__ __forceinline__ u16 f2b(float f) {
    __bf16 h = (__bf16)f;                      // RNE hardware convert
    union { __bf16 hh; u16 uu; } c; c.hh = h; return c.uu;
}
static __device__ __forceinline__ float b2f(u16 u) {
    return __uint_as_float(((unsigned)u) << 16);
}

// LDS XOR swizzle for [rows][128 bf16] tiles read as ds_read_b128 down rows
// (T2, §6 G4): XOR 16B-granule index with (row&7).
#define SWZ(rr, cc) ((((rr) * 128) + (cc)) ^ (((rr) & 7) << 3))

// ---------------------------------------------------------------------------
// K0: wqkvT[f][k] = bf16(w_qkv[k][f]); w_outT[c][d] = bf16(w_out[d][c])
// ---------------------------------------------------------------------------
__global__ void k_prep_w(const float* __restrict__ wqkv, const float* __restrict__ wout,
                         u16* __restrict__ wqkvT, u16* __restrict__ woutT) {
    int t = blockIdx.x * 256 + threadIdx.x;     // 65536 total
    if (t < F3 * CIN) {
        int f = t >> 7, k = t & 127;
        wqkvT[t] = f2b(wqkv[(size_t)k * F3 + f]);
    } else {
        int j = t - F3 * CIN;                   // 16384
        int c = j >> 7, d = j & 127;
        woutT[j] = f2b(wout[(size_t)d * 128 + c]);
    }
}

// ---------------------------------------------------------------------------
// K1: qkv GEMM via mfma_f32_16x16x32_bf16. Tile 128 tok x 128 f, K=128.
// grid 3072 = 1024 m-tiles x 3 fc. Epilogue per fc:
//   fc0 (q): q_g[n][128] row-major (scalar 2B stores)
//   fc1 (k): ekT[f][n] = bf16(exp(k))  (u16x4 8B stores, transposed-contiguous)
//   fc2 (v): vT [f][n]                 (same)
// ---------------------------------------------------------------------------
__global__ __launch_bounds__(256, 2) void k_qkv(
    const float* __restrict__ x, const u16* __restrict__ wT,
    u16* __restrict__ q_g, u16* __restrict__ ekT, u16* __restrict__ vT)
{
    extern __shared__ u16 lds[];
    u16* As = lds;            // 128x128 bf16, swizzled
    u16* Bs = lds + 16384;    // 128x128 bf16 (rows = f, cols = k), swizzled

    const int t  = threadIdx.x;
    const int fc = blockIdx.x % 3;
    const long row0 = (long)(blockIdx.x / 3) * 128;

    // stage A: 128 rows x 32 float4, convert to bf16, swizzled 8B writes
#pragma unroll
    for (int i = 0; i < 16; ++i) {
        int idx = i * 256 + t;
        int r = idx >> 5, c4 = idx & 31;
        float4 v = reinterpret_cast<const float4*>(x + (row0 + r) * CIN)[c4];
        u16x4 b; b[0] = f2b(v.x); b[1] = f2b(v.y); b[2] = f2b(v.z); b[3] = f2b(v.w);
        *reinterpret_cast<u16x4*>(&As[SWZ(r, c4 * 4)]) = b;
    }
    // stage B: 128 f-rows x 16 u16x8 units, swizzled 16B writes
#pragma unroll
    for (int i = 0; i < 8; ++i) {
        int idx = i * 256 + t;
        int f = idx >> 4, u = idx & 15;
        u16x8 wv = *reinterpret_cast<const u16x8*>(wT + (size_t)(fc * 128 + f) * 128 + u * 8);
        *reinterpret_cast<u16x8*>(&Bs[SWZ(f, u * 8)]) = wv;
    }
    __syncthreads();

    const int lane = t & 63, wid = t >> 6;
    const int wm = (wid >> 1) * 64, wn = (wid & 1) * 64;
    const int lr = lane & 15, lk = lane >> 4;

    f32x4 acc[4][4];
#pragma unroll
    for (int mi = 0; mi < 4; ++mi)
#pragma unroll
        for (int ni = 0; ni < 4; ++ni)
            acc[mi][ni] = (f32x4){0.f, 0.f, 0.f, 0.f};

#pragma unroll
    for (int ks = 0; ks < 4; ++ks) {
        bf16x8 a[4], b[4];
        const int kc = ks * 32 + lk * 8;
#pragma unroll
        for (int mi = 0; mi < 4; ++mi)
            a[mi] = *reinterpret_cast<const bf16x8*>(&As[SWZ(wm + mi * 16 + lr, kc)]);
#pragma unroll
        for (int ni = 0; ni < 4; ++ni)
            b[ni] = *reinterpret_cast<const bf16x8*>(&Bs[SWZ(wn + ni * 16 + lr, kc)]);
#pragma unroll
        for (int mi = 0; mi < 4; ++mi)
#pragma unroll
            for (int ni = 0; ni < 4; ++ni)
                acc[mi][ni] = __builtin_amdgcn_mfma_f32_16x16x32_bf16(a[mi], b[ni], acc[mi][ni], 0, 0, 0);
    }

    // C layout: col = lane&15, row = (lane>>4)*4 + reg (m89-verified)
    if (fc == 0) {
#pragma unroll
        for (int mi = 0; mi < 4; ++mi)
#pragma unroll
            for (int ni = 0; ni < 4; ++ni) {
                const int col = wn + ni * 16 + lr;
                const long rbase = row0 + wm + mi * 16 + lk * 4;
#pragma unroll
                for (int r = 0; r < 4; ++r)
                    q_g[(rbase + r) * 128 + col] = f2b(acc[mi][ni][r]);
            }
    } else {
        u16* dstT = (fc == 1) ? ekT : vT;
        const bool ise = (fc == 1);
#pragma unroll
        for (int mi = 0; mi < 4; ++mi)
#pragma unroll
            for (int ni = 0; ni < 4; ++ni) {
                const int col = wn + ni * 16 + lr;
                const long rbase = row0 + wm + mi * 16 + lk * 4;
                u16x4 pk;
#pragma unroll
                for (int r = 0; r < 4; ++r) {
                    float vv = acc[mi][ni][r];
                    if (ise) vv = __expf(vv);
                    pk[r] = f2b(vv);
                }
                *reinterpret_cast<u16x4*>(dstT + (size_t)col * TOKENS + rbase) = pk;
            }
    }
}

// ---------------------------------------------------------------------------
// K2: ctx_raw[b,h,d,e] += sum_n ekT[h*32+d][n] * vT[h*32+e][n]  (MFMA)
//     ksum[b,h,d]      += sum_n ekT[h*32+d][n]                  (VALU)
// grid 512 = 32 b x 16 chunks of 256 tokens (2 subtiles of 128).
// 4 waves, wave = head. LDS 64KB (2 x [128][128] bf16, granule-swizzled).
// ---------------------------------------------------------------------------
__global__ __launch_bounds__(256, 2) void k_ctx(
    const u16* __restrict__ ekT, const u16* __restrict__ vT,
    float* __restrict__ ctx_raw, float* __restrict__ ksum)
{
    extern __shared__ u16 lds2[];
    u16* ek = lds2;           // [128][128] swizzled
    u16* vv = lds2 + 16384;

    const int t = threadIdx.x;
    const int b = blockIdx.x >> 4;
    const int chunk = blockIdx.x & 15;
    const long n0 = (long)b * NTOK + chunk * 256;

    const int lane = t & 63, h = t >> 6;
    const int lr = lane & 15, lk = lane >> 4;

    f32x4 acc[2][2];
#pragma unroll
    for (int i = 0; i < 2; ++i)
#pragma unroll
        for (int j = 0; j < 2; ++j) acc[i][j] = (f32x4){0.f, 0.f, 0.f, 0.f};
    float ksr = 0.f;

    const int unit = t & 15;
    const int fb = t >> 4;

    for (int sub = 0; sub < 2; ++sub) {
        __syncthreads();
        const long nb = n0 + sub * 128;
#pragma unroll
        for (int p = 0; p < 8; ++p) {
            int f = fb * 8 + p;
            size_t goff = (size_t)f * TOKENS + nb + unit * 8;
            *reinterpret_cast<u16x8*>(&ek[SWZ(f, unit * 8)]) =
                *reinterpret_cast<const u16x8*>(ekT + goff);
            *reinterpret_cast<u16x8*>(&vv[SWZ(f, unit * 8)]) =
                *reinterpret_cast<const u16x8*>(vT + goff);
        }
        __syncthreads();

#pragma unroll
        for (int ks = 0; ks < 4; ++ks) {
            const int kn = ks * 32 + lk * 8;
            bf16x8 a0 = *reinterpret_cast<const bf16x8*>(&ek[SWZ(h * 32 + lr, kn)]);
            bf16x8 a1 = *reinterpret_cast<const bf16x8*>(&ek[SWZ(h * 32 + 16 + lr, kn)]);
            bf16x8 b0 = *reinterpret_cast<const bf16x8*>(&vv[SWZ(h * 32 + lr, kn)]);
            bf16x8 b1 = *reinterpret_cast<const bf16x8*>(&vv[SWZ(h * 32 + 16 + lr, kn)]);
            acc[0][0] = __builtin_amdgcn_mfma_f32_16x16x32_bf16(a0, b0, acc[0][0], 0, 0, 0);
            acc[0][1] = __builtin_amdgcn_mfma_f32_16x16x32_bf16(a0, b1, acc[0][1], 0, 0, 0);
            acc[1][0] = __builtin_amdgcn_mfma_f32_16x16x32_bf16(a1, b0, acc[1][0], 0, 0, 0);
            acc[1][1] = __builtin_amdgcn_mfma_f32_16x16x32_bf16(a1, b1, acc[1][1], 0, 0, 0);
        }
        // ksum partial: lane d = lane&31, half = lane>>5 sums 64 n
        {
            const int d = lane & 31, half = lane >> 5;
            const int f = h * 32 + d;
#pragma unroll
            for (int j = 0; j < 8; ++j) {
                int n = half * 64 + j * 8;
                u16x8 e8 = *reinterpret_cast<const u16x8*>(&ek[SWZ(f, n)]);
#pragma unroll
                for (int i = 0; i < 8; ++i) ksr += b2f(e8[i]);
            }
        }
    }

    ksr += __shfl_xor(ksr, 32);
    if (lane < 32) atomicAdd(ksum + b * 128 + h * 32 + lane, ksr);

#pragma unroll
    for (int df = 0; df < 2; ++df)
#pragma unroll
        for (int ef = 0; ef < 2; ++ef) {
            float* cp = ctx_raw + (size_t)b * 4096 + h * 1024 + (df * 16 + lk * 4) * 32 + ef * 16 + lr;
#pragma unroll
            for (int r = 0; r < 4; ++r)
                atomicAdd(cp + r * 32, acc[df][ef][r]);
        }
}

// ---------------------------------------------------------------------------
// K3: per 128 tokens: q-softmax -> out_tok = ctxT.qs (MFMA, per head) ->
//     y = ot @ w_outT + b (MFMA 128^3) -> fused LayerNorm -> store fp32.
// 4 waves. LDS: ctxT 8K + qs/ot 32K + wB 32K + sums 2K = 75776 B -> 2 blk/CU.
// ---------------------------------------------------------------------------
__global__ __launch_bounds__(256, 2) void k_out(
    const u16* __restrict__ q_g, const float* __restrict__ ctx_raw, const float* __restrict__ ksum,
    const u16* __restrict__ woutT, const float* __restrict__ b_out, const float* __restrict__ ln_scale,
    float* __restrict__ out)
{
    extern __shared__ u16 sm16[];
    u16* ctxT = sm16;                    // [4][32 e][32 d] bf16, d-granule swizzled by e&3
    u16* qs   = sm16 + 4096;             // [128][128] bf16 SWZ (later overlaid with ot)
    u16* wB   = sm16 + 4096 + 16384;     // [128 c][128 d] bf16 SWZ
    float* sums = (float*)(sm16 + 4096 + 2 * 16384);  // s1[256], s2[256]

    const int t = threadIdx.x;
    const long row0 = (long)blockIdx.x * 128;
    const int b = (int)(row0 >> 12);
    const int lane = t & 63, wid = t >> 6;
    const int lr = lane & 15, lk = lane >> 4;

    // stage wB
#pragma unroll
    for (int i = 0; i < 8; ++i) {
        int j = i * 256 + t;
        int c = j >> 4, u = j & 15;
        *reinterpret_cast<u16x8*>(&wB[SWZ(c, u * 8)]) =
            *reinterpret_cast<const u16x8*>(woutT + (size_t)c * 128 + u * 8);
    }
    // normalized context, transposed per head: ctxT[h][e][d]
#pragma unroll
    for (int i = 0; i < 16; ++i) {
        int j = i * 256 + t;
        int h = j >> 10, d = (j >> 5) & 31, e = j & 31;
        float val = ctx_raw[(size_t)b * 4096 + j] / (ksum[b * 128 + (j >> 5)] * 4096.0f);
        ctxT[h * 1024 + e * 32 + (d ^ ((e & 3) << 3))] = f2b(val);
    }
    // q softmax: thread owns (row = t>>1, 64 ch = 2 heads)
    {
        const int row = t >> 1, side = t & 1;
        const u16* qp = q_g + (size_t)(row0 + row) * 128 + side * 64;
#pragma unroll
        for (int hh = 0; hh < 2; ++hh) {
            float f[32];
#pragma unroll
            for (int g = 0; g < 4; ++g) {
                u16x8 v8 = *reinterpret_cast<const u16x8*>(qp + hh * 32 + g * 8);
#pragma unroll
                for (int i = 0; i < 8; ++i) f[g * 8 + i] = b2f(v8[i]);
            }
            float m = f[0];
#pragma unroll
            for (int i = 1; i < 32; ++i) m = fmaxf(m, f[i]);
            float s = 0.f;
#pragma unroll
            for (int i = 0; i < 32; ++i) { f[i] = __expf(f[i] - m); s += f[i]; }
            float sc = 1.0f / (s * 5.65685424949238f);   // includes 1/sqrt(32)
#pragma unroll
            for (int g = 0; g < 4; ++g) {
                u16x8 o;
#pragma unroll
                for (int i = 0; i < 8; ++i) o[i] = f2b(f[g * 8 + i] * sc);
                *reinterpret_cast<u16x8*>(&qs[SWZ(row, side * 64 + hh * 32 + g * 8)]) = o;
            }
        }
    }
    __syncthreads();

    // phase A: out_tok^T per head: D[e][n] = sum_d ctxT[e][d] * qs[n][h*32+d]
    const int wn2 = wid * 32;
    f32x4 pa[4][2][2];
    {
        bf16x8 actx[4][2], bqs[4][2];
#pragma unroll
        for (int h = 0; h < 4; ++h)
#pragma unroll
            for (int ef = 0; ef < 2; ++ef) {
                int e = ef * 16 + lr;
                actx[h][ef] = *reinterpret_cast<const bf16x8*>(
                    &ctxT[h * 1024 + e * 32 + ((lk * 8) ^ ((e & 3) << 3))]);
            }
#pragma unroll
        for (int h = 0; h < 4; ++h)
#pragma unroll
            for (int nf = 0; nf < 2; ++nf)
                bqs[h][nf] = *reinterpret_cast<const bf16x8*>(
                    &qs[SWZ(wn2 + nf * 16 + lr, h * 32 + lk * 8)]);
#pragma unroll
        for (int h = 0; h < 4; ++h)
#pragma unroll
            for (int ef = 0; ef < 2; ++ef)
#pragma unroll
                for (int nf = 0; nf < 2; ++nf)
                    pa[h][ef][nf] = __builtin_amdgcn_mfma_f32_16x16x32_bf16(
                        actx[h][ef], bqs[h][nf], (f32x4){0.f, 0.f, 0.f, 0.f}, 0, 0, 0);
    }
    __syncthreads();
    // write ot[n][c] into qs region (row-major for phase-B A-operand)
#pragma unroll
    for (int h = 0; h < 4; ++h)
#pragma unroll
        for (int ef = 0; ef < 2; ++ef)
#pragma unroll
            for (int nf = 0; nf < 2; ++nf) {
                int n = wn2 + nf * 16 + lr;
                int cb = h * 32 + ef * 16 + lk * 4;
                u16x4 pk;
#pragma unroll
                for (int r = 0; r < 4; ++r) pk[r] = f2b(pa[h][ef][nf][r]);
                *reinterpret_cast<u16x4*>(&qs[SWZ(n, cb)]) = pk;
            }
    __syncthreads();

    // phase B: y[n][c] = sum_d ot[n][d] * w_out[d][c]
    const int wm = (wid >> 1) * 64, wn = (wid & 1) * 64;
    f32x4 acc[4][4];
#pragma unroll
    for (int mi = 0; mi < 4; ++mi)
#pragma unroll
        for (int ni = 0; ni < 4; ++ni) acc[mi][ni] = (f32x4){0.f, 0.f, 0.f, 0.f};
#pragma unroll
    for (int ks = 0; ks < 4; ++ks) {
        bf16x8 a[4], bb[4];
        const int kc = ks * 32 + lk * 8;
#pragma unroll
        for (int mi = 0; mi < 4; ++mi)
            a[mi] = *reinterpret_cast<const bf16x8*>(&qs[SWZ(wm + mi * 16 + lr, kc)]);
#pragma unroll
        for (int ni = 0; ni < 4; ++ni)
            bb[ni] = *reinterpret_cast<const bf16x8*>(&wB[SWZ(wn + ni * 16 + lr, kc)]);
#pragma unroll
        for (int mi = 0; mi < 4; ++mi)
#pragma unroll
            for (int ni = 0; ni < 4; ++ni)
                acc[mi][ni] = __builtin_amdgcn_mfma_f32_16x16x32_bf16(a[mi], bb[ni], acc[mi][ni], 0, 0, 0);
    }

    // fused LayerNorm. C layout: col c = wn+ni*16+lr, row = wm+mi*16+lk*4+r.
    float bias[4], lns[4];
#pragma unroll
    for (int ni = 0; ni < 4; ++ni) {
        int c = wn + ni * 16 + lr;
        bias[ni] = b_out[c];
        lns[ni]  = ln_scale[c];
    }
    float rs1[4][4], rs2[4][4];
#pragma unroll
    for (int mi = 0; mi < 4; ++mi)
#pragma unroll
        for (int r = 0; r < 4; ++r) {
            float s1 = 0.f, s2 = 0.f;
#pragma unroll
            for (int ni = 0; ni < 4; ++ni) {
                float v = acc[mi][ni][r] + bias[ni];
                s1 += v; s2 += v * v;
            }
            rs1[mi][r] = s1; rs2[mi][r] = s2;
        }
#pragma unroll
    for (int mask = 1; mask <= 8; mask <<= 1)
#pragma unroll
        for (int mi = 0; mi < 4; ++mi)
#pragma unroll
            for (int r = 0; r < 4; ++r) {
                rs1[mi][r] += __shfl_xor(rs1[mi][r], mask);
                rs2[mi][r] += __shfl_xor(rs2[mi][r], mask);
            }
    if (lr == 0) {
        const int hcol = wn >> 6;
#pragma unroll
        for (int mi = 0; mi < 4; ++mi)
#pragma unroll
            for (int r = 0; r < 4; ++r) {
                int row = wm + mi * 16 + lk * 4 + r;
                sums[row * 2 + hcol]       = rs1[mi][r];
                sums[256 + row * 2 + hcol] = rs2[mi][r];
            }
    }
    __syncthreads();
#pragma unroll
    for (int mi = 0; mi < 4; ++mi)
#pragma unroll
        for (int r = 0; r < 4; ++r) {
            int row = wm + mi * 16 + lk * 4 + r;
            float S1 = sums[row * 2] + sums[row * 2 + 1];
            float S2 = sums[256 + row * 2] + sums[256 + row * 2 + 1];
            float mu  = S1 * (1.0f / 128.0f);
            float var = S2 * (1.0f / 128.0f) - mu * mu;
            float rstd = rsqrtf(var + LN_EPS);
            float* op = out + (size_t)(row0 + row) * 128;
#pragma unroll
            for (int ni = 0; ni < 4; ++ni) {
                float v = acc[mi][ni][r] + bias[ni];
                op[wn + ni * 16 + lr] = (v - mu) * rstd * lns[ni];
            }
        }
}

// ---------------------------------------------------------------------------
extern "C" void kernel_launch(void* const* d_in, const int* in_sizes, int n_in,
                              void* d_out, int out_size, void* d_ws, size_t ws_size,
                              hipStream_t stream) {
    const float* x        = (const float*)d_in[0];
    const float* w_qkv    = (const float*)d_in[1];
    const float* w_out    = (const float*)d_in[2];
    const float* b_out    = (const float*)d_in[3];
    const float* ln_scale = (const float*)d_in[4];
    float* out = (float*)d_out;

    const size_t NTOT = (size_t)TOKENS * 128;   // 16.78M
    u16*   q_g    = (u16*)d_ws;                 // [n][128]
    u16*   ekT    = q_g + NTOT;                 // [128 f][TOKENS]
    u16*   vT     = ekT + NTOT;                 // [128 f][TOKENS]
    u16*   wqkvT  = vT + NTOT;                  // [384][128]
    u16*   woutT  = wqkvT + (size_t)F3 * CIN;   // [128][128]
    float* ctx_raw = (float*)(woutT + 128 * 128);   // [32][4][32][32]
    float* ksum    = ctx_raw + 131072;              // [32][128]
    size_t need = (3 * NTOT + F3 * CIN + 128 * 128) * 2 + (131072 + 4096) * 4;
    if (ws_size < need) return;

    (void)hipMemsetAsync(ctx_raw, 0, (131072 + 4096) * sizeof(float), stream);

    const int lds_qkv = 2 * 16384 * sizeof(u16);             // 64 KB
    const int lds_ctx = 2 * 16384 * sizeof(u16);             // 64 KB
    const int lds_out = (4096 + 2 * 16384) * 2 + 512 * 4;    // 75776 B
    (void)hipFuncSetAttribute(reinterpret_cast<const void*>(k_qkv),
                              hipFuncAttributeMaxDynamicSharedMemorySize, lds_qkv);
    (void)hipFuncSetAttribute(reinterpret_cast<const void*>(k_ctx),
                              hipFuncAttributeMaxDynamicSharedMemorySize, lds_ctx);
    (void)hipFuncSetAttribute(reinterpret_cast<const void*>(k_out),
                              hipFuncAttributeMaxDynamicSharedMemorySize, lds_out);

    hipLaunchKernelGGL(k_prep_w, dim3(256), dim3(256), 0, stream, w_qkv, w_out, wqkvT, woutT);
    hipLaunchKernelGGL(k_qkv, dim3(3072), dim3(256), lds_qkv, stream, x, wqkvT, q_g, ekT, vT);
    hipLaunchKernelGGL(k_ctx, dim3(512), dim3(256), lds_ctx, stream, ekT, vT, ctx_raw, ksum);
    hipLaunchKernelGGL(k_out, dim3(1024), dim3(256), lds_out, stream, q_g, ctx_raw, ksum,
                       woutT, b_out, ln_scale, out);
}

// Round 7
// 196.625 us; speedup vs baseline: 2.3210x; 1.0336x over previous
//
#include <hip/hip_runtime.h>
#include <hip/hip_bf16.h>
#include <math.h>

// Problem constants
#define TOKENS 131072      // 32*64*64 tokens
#define CIN    128         // input channels
#define F3     384         // 3*DIM qkv output channels
#define NTOK   4096        // tokens per batch (64*64)
#define LN_EPS 1e-5f

typedef unsigned short u16;
typedef u16   u16x4 __attribute__((ext_vector_type(4)));
typedef u16   u16x8 __attribute__((ext_vector_type(8)));
typedef __bf16 bf16x8 __attribute__((ext_vector_type(8)));
typedef float f32x4  __attribute__((ext_vector_type(4)));

static __device__ __forceinline__ u16 f2b(float f) {
    __bf16 h = (__bf16)f;                      // RNE hardware convert
    union { __bf16 hh; u16 uu; } c; c.hh = h; return c.uu;
}
static __device__ __forceinline__ float b2f(u16 u) {
    return __uint_as_float(((unsigned)u) << 16);
}

// LDS XOR swizzle for [rows][128 bf16] tiles read as ds_read_b128 down rows
// (T2, §6 G4): XOR 16B-granule index with (row&7).
#define SWZ(rr, cc) ((((rr) * 128) + (cc)) ^ (((rr) & 7) << 3))

// ---------------------------------------------------------------------------
// K0: wqkvT[f][k] = bf16(w_qkv[k][f]); w_outT[c][d] = bf16(w_out[d][c])
// ---------------------------------------------------------------------------
__global__ void k_prep_w(const float* __restrict__ wqkv, const float* __restrict__ wout,
                         u16* __restrict__ wqkvT, u16* __restrict__ woutT) {
    int t = blockIdx.x * 256 + threadIdx.x;     // 65536 total
    if (t < F3 * CIN) {
        int f = t >> 7, k = t & 127;
        wqkvT[t] = f2b(wqkv[(size_t)k * F3 + f]);
    } else {
        int j = t - F3 * CIN;                   // 16384
        int c = j >> 7, d = j & 127;
        woutT[j] = f2b(wout[(size_t)d * 128 + c]);
    }
}

// ---------------------------------------------------------------------------
// K1: qkv GEMM via mfma_f32_16x16x32_bf16. One block per 128-token tile;
// fc chunks looped INSIDE the block so x is staged (and fetched) exactly once.
// B (96 KB total weights) is L2-resident across all blocks. Epilogue per fc:
//   fc0 (q): q_g[n][128] row-major
//   fc1 (k): ekT[f][n] = bf16(exp(k))  (u16x4 8B transposed-contiguous stores)
//   fc2 (v): vT [f][n]
// ---------------------------------------------------------------------------
__global__ __launch_bounds__(256, 2) void k_qkv(
    const float* __restrict__ x, const u16* __restrict__ wT,
    u16* __restrict__ q_g, u16* __restrict__ ekT, u16* __restrict__ vT)
{
    extern __shared__ u16 lds[];
    u16* As = lds;            // 128x128 bf16, swizzled (32 KB)
    u16* Bs = lds + 16384;    // 128x128 bf16 (rows = f, cols = k), swizzled (32 KB)

    const int t = threadIdx.x;
    const long row0 = (long)blockIdx.x * 128;

    // stage A once: 128 rows x 32 float4, convert to bf16, swizzled 8B writes
#pragma unroll
    for (int i = 0; i < 16; ++i) {
        int idx = i * 256 + t;
        int r = idx >> 5, c4 = idx & 31;
        float4 v = reinterpret_cast<const float4*>(x + (row0 + r) * CIN)[c4];
        u16x4 bq; bq[0] = f2b(v.x); bq[1] = f2b(v.y); bq[2] = f2b(v.z); bq[3] = f2b(v.w);
        *reinterpret_cast<u16x4*>(&As[SWZ(r, c4 * 4)]) = bq;
    }

    const int lane = t & 63, wid = t >> 6;
    const int wm = (wid >> 1) * 64, wn = (wid & 1) * 64;
    const int lr = lane & 15, lk = lane >> 4;

#pragma unroll
    for (int fc = 0; fc < 3; ++fc) {
        __syncthreads();   // fc0: A ready; fc>0: prior reads of Bs done
        // stage B chunk: 128 f-rows x 16 u16x8 units, swizzled 16B writes
#pragma unroll
        for (int i = 0; i < 8; ++i) {
            int idx = i * 256 + t;
            int f = idx >> 4, u = idx & 15;
            u16x8 wv = *reinterpret_cast<const u16x8*>(wT + (size_t)(fc * 128 + f) * 128 + u * 8);
            *reinterpret_cast<u16x8*>(&Bs[SWZ(f, u * 8)]) = wv;
        }
        __syncthreads();

        f32x4 acc[4][4];
#pragma unroll
        for (int mi = 0; mi < 4; ++mi)
#pragma unroll
            for (int ni = 0; ni < 4; ++ni)
                acc[mi][ni] = (f32x4){0.f, 0.f, 0.f, 0.f};

#pragma unroll
        for (int ks = 0; ks < 4; ++ks) {
            bf16x8 a[4], b[4];
            const int kc = ks * 32 + lk * 8;
#pragma unroll
            for (int mi = 0; mi < 4; ++mi)
                a[mi] = *reinterpret_cast<const bf16x8*>(&As[SWZ(wm + mi * 16 + lr, kc)]);
#pragma unroll
            for (int ni = 0; ni < 4; ++ni)
                b[ni] = *reinterpret_cast<const bf16x8*>(&Bs[SWZ(wn + ni * 16 + lr, kc)]);
#pragma unroll
            for (int mi = 0; mi < 4; ++mi)
#pragma unroll
                for (int ni = 0; ni < 4; ++ni)
                    acc[mi][ni] = __builtin_amdgcn_mfma_f32_16x16x32_bf16(a[mi], b[ni], acc[mi][ni], 0, 0, 0);
        }

        // C layout: col = lane&15, row = (lane>>4)*4 + reg (m89-verified)
        if (fc == 0) {
#pragma unroll
            for (int mi = 0; mi < 4; ++mi)
#pragma unroll
                for (int ni = 0; ni < 4; ++ni) {
                    const int col = wn + ni * 16 + lr;
                    const long rbase = row0 + wm + mi * 16 + lk * 4;
#pragma unroll
                    for (int r = 0; r < 4; ++r)
                        q_g[(rbase + r) * 128 + col] = f2b(acc[mi][ni][r]);
                }
        } else {
            u16* dstT = (fc == 1) ? ekT : vT;
            const bool ise = (fc == 1);
#pragma unroll
            for (int mi = 0; mi < 4; ++mi)
#pragma unroll
                for (int ni = 0; ni < 4; ++ni) {
                    const int col = wn + ni * 16 + lr;
                    const long rbase = row0 + wm + mi * 16 + lk * 4;
                    u16x4 pk;
#pragma unroll
                    for (int r = 0; r < 4; ++r) {
                        float vv = acc[mi][ni][r];
                        if (ise) vv = __expf(vv);
                        pk[r] = f2b(vv);
                    }
                    *reinterpret_cast<u16x4*>(dstT + (size_t)col * TOKENS + rbase) = pk;
                }
        }
    }
}

// ---------------------------------------------------------------------------
// K2: ctx_part[b,chunk,h,d,e] = sum_{n in chunk} ekT[h*32+d][n] * vT[h*32+e][n]
//     ksum_part[b,chunk,h,d]  = sum_{n in chunk} ekT[h*32+d][n]
// NO atomics: plain partial-sum stores, reduced by k_red.
// grid 512 = 32 b x 16 chunks of 256 tokens (2 subtiles of 128).
// 4 waves, wave = head. LDS 64KB (2 x [128][128] bf16, granule-swizzled).
// ---------------------------------------------------------------------------
__global__ __launch_bounds__(256, 2) void k_ctx(
    const u16* __restrict__ ekT, const u16* __restrict__ vT,
    float* __restrict__ ctx_part, float* __restrict__ ksum_part)
{
    extern __shared__ u16 lds2[];
    u16* ek = lds2;           // [128][128] swizzled
    u16* vv = lds2 + 16384;

    const int t = threadIdx.x;
    const int b = blockIdx.x >> 4;
    const int chunk = blockIdx.x & 15;
    const long n0 = (long)b * NTOK + chunk * 256;

    const int lane = t & 63, h = t >> 6;
    const int lr = lane & 15, lk = lane >> 4;

    f32x4 acc[2][2];
#pragma unroll
    for (int i = 0; i < 2; ++i)
#pragma unroll
        for (int j = 0; j < 2; ++j) acc[i][j] = (f32x4){0.f, 0.f, 0.f, 0.f};
    float ksr = 0.f;

    const int unit = t & 15;
    const int fb = t >> 4;

    for (int sub = 0; sub < 2; ++sub) {
        __syncthreads();
        const long nb = n0 + sub * 128;
#pragma unroll
        for (int p = 0; p < 8; ++p) {
            int f = fb * 8 + p;
            size_t goff = (size_t)f * TOKENS + nb + unit * 8;
            *reinterpret_cast<u16x8*>(&ek[SWZ(f, unit * 8)]) =
                *reinterpret_cast<const u16x8*>(ekT + goff);
            *reinterpret_cast<u16x8*>(&vv[SWZ(f, unit * 8)]) =
                *reinterpret_cast<const u16x8*>(vT + goff);
        }
        __syncthreads();

#pragma unroll
        for (int ks = 0; ks < 4; ++ks) {
            const int kn = ks * 32 + lk * 8;
            bf16x8 a0 = *reinterpret_cast<const bf16x8*>(&ek[SWZ(h * 32 + lr, kn)]);
            bf16x8 a1 = *reinterpret_cast<const bf16x8*>(&ek[SWZ(h * 32 + 16 + lr, kn)]);
            bf16x8 b0 = *reinterpret_cast<const bf16x8*>(&vv[SWZ(h * 32 + lr, kn)]);
            bf16x8 b1 = *reinterpret_cast<const bf16x8*>(&vv[SWZ(h * 32 + 16 + lr, kn)]);
            acc[0][0] = __builtin_amdgcn_mfma_f32_16x16x32_bf16(a0, b0, acc[0][0], 0, 0, 0);
            acc[0][1] = __builtin_amdgcn_mfma_f32_16x16x32_bf16(a0, b1, acc[0][1], 0, 0, 0);
            acc[1][0] = __builtin_amdgcn_mfma_f32_16x16x32_bf16(a1, b0, acc[1][0], 0, 0, 0);
            acc[1][1] = __builtin_amdgcn_mfma_f32_16x16x32_bf16(a1, b1, acc[1][1], 0, 0, 0);
        }
        // ksum partial: lane d = lane&31, half = lane>>5 sums 64 n
        {
            const int d = lane & 31, half = lane >> 5;
            const int f = h * 32 + d;
#pragma unroll
            for (int j = 0; j < 8; ++j) {
                int n = half * 64 + j * 8;
                u16x8 e8 = *reinterpret_cast<const u16x8*>(&ek[SWZ(f, n)]);
#pragma unroll
                for (int i = 0; i < 8; ++i) ksr += b2f(e8[i]);
            }
        }
    }

    ksr += __shfl_xor(ksr, 32);
    if (lane < 32) ksum_part[((size_t)b * 16 + chunk) * 128 + h * 32 + lane] = ksr;

    float* cp = ctx_part + ((size_t)b * 16 + chunk) * 4096 + h * 1024;
#pragma unroll
    for (int df = 0; df < 2; ++df)
#pragma unroll
        for (int ef = 0; ef < 2; ++ef)
#pragma unroll
            for (int r = 0; r < 4; ++r)
                cp[(df * 16 + lk * 4 + r) * 32 + ef * 16 + lr] = acc[df][ef][r];
}

// ---------------------------------------------------------------------------
// K2b: reduce partials, normalize, emit pre-swizzled bf16 ctxT layout:
//      ctxg[b][h*1024 + e*32 + (d ^ ((e&3)<<3))] = ctx[h,d,e]/(ksum[h,d]*N)
// grid 32 (one block per b), 256 thr.
// ---------------------------------------------------------------------------
__global__ void k_red(const float* __restrict__ ctx_part, const float* __restrict__ ksum_part,
                      u16* __restrict__ ctxg) {
    __shared__ float ks[128];
    const int b = blockIdx.x, t = threadIdx.x;
    const float* cp = ctx_part + (size_t)b * 16 * 4096;
    const float* kp = ksum_part + (size_t)b * 16 * 128;
    if (t < 128) {
        float s = 0.f;
#pragma unroll
        for (int c = 0; c < 16; ++c) s += kp[c * 128 + t];
        ks[t] = 1.0f / (s * 4096.0f);
    }
    __syncthreads();
#pragma unroll
    for (int i = 0; i < 16; ++i) {
        int j = i * 256 + t;              // = h*1024 + d*32 + e
        float s = 0.f;
#pragma unroll
        for (int c = 0; c < 16; ++c) s += cp[c * 4096 + j];
        int h = j >> 10, d = (j >> 5) & 31, e = j & 31;
        ctxg[(size_t)b * 4096 + h * 1024 + e * 32 + (d ^ ((e & 3) << 3))] = f2b(s * ks[j >> 5]);
    }
}

// ---------------------------------------------------------------------------
// K3: per 128 tokens: q-softmax -> out_tok = ctxT.qs (MFMA, per head) ->
//     y = ot @ w_outT + b (MFMA 128^3) -> fused LayerNorm -> store fp32.
// 4 waves. LDS: ctxT 8K + qs/ot 32K + wB 32K + sums 2K = 75776 B -> 2 blk/CU.
// ---------------------------------------------------------------------------
__global__ __launch_bounds__(256, 2) void k_out(
    const u16* __restrict__ q_g, const u16* __restrict__ ctxg,
    const u16* __restrict__ woutT, const float* __restrict__ b_out, const float* __restrict__ ln_scale,
    float* __restrict__ out)
{
    extern __shared__ u16 sm16[];
    u16* ctxT = sm16;                    // [4][32 e][32 d] bf16, d-granule swizzled by e&3
    u16* qs   = sm16 + 4096;             // [128][128] bf16 SWZ (later overlaid with ot)
    u16* wB   = sm16 + 4096 + 16384;     // [128 c][128 d] bf16 SWZ
    float* sums = (float*)(sm16 + 4096 + 2 * 16384);  // s1[256], s2[256]

    const int t = threadIdx.x;
    const long row0 = (long)blockIdx.x * 128;
    const int b = (int)(row0 >> 12);
    const int lane = t & 63, wid = t >> 6;
    const int lr = lane & 15, lk = lane >> 4;

    // stage wB
#pragma unroll
    for (int i = 0; i < 8; ++i) {
        int j = i * 256 + t;
        int c = j >> 4, u = j & 15;
        *reinterpret_cast<u16x8*>(&wB[SWZ(c, u * 8)]) =
            *reinterpret_cast<const u16x8*>(woutT + (size_t)c * 128 + u * 8);
    }
    // ctxT: straight 8 KB copy (k_red already normalized + swizzled)
#pragma unroll
    for (int i = 0; i < 2; ++i) {
        int j = i * 256 + t;
        *reinterpret_cast<u16x8*>(&ctxT[j * 8]) =
            *reinterpret_cast<const u16x8*>(ctxg + (size_t)b * 4096 + j * 8);
    }
    // q softmax: thread owns (row = t>>1, 64 ch = 2 heads)
    {
        const int row = t >> 1, side = t & 1;
        const u16* qp = q_g + (size_t)(row0 + row) * 128 + side * 64;
#pragma unroll
        for (int hh = 0; hh < 2; ++hh) {
            float f[32];
#pragma unroll
            for (int g = 0; g < 4; ++g) {
                u16x8 v8 = *reinterpret_cast<const u16x8*>(qp + hh * 32 + g * 8);
#pragma unroll
                for (int i = 0; i < 8; ++i) f[g * 8 + i] = b2f(v8[i]);
            }
            float m = f[0];
#pragma unroll
            for (int i = 1; i < 32; ++i) m = fmaxf(m, f[i]);
            float s = 0.f;
#pragma unroll
            for (int i = 0; i < 32; ++i) { f[i] = __expf(f[i] - m); s += f[i]; }
            float sc = 1.0f / (s * 5.65685424949238f);   // includes 1/sqrt(32)
#pragma unroll
            for (int g = 0; g < 4; ++g) {
                u16x8 o;
#pragma unroll
                for (int i = 0; i < 8; ++i) o[i] = f2b(f[g * 8 + i] * sc);
                *reinterpret_cast<u16x8*>(&qs[SWZ(row, side * 64 + hh * 32 + g * 8)]) = o;
            }
        }
    }
    __syncthreads();

    // phase A: out_tok^T per head: D[e][n] = sum_d ctxT[e][d] * qs[n][h*32+d]
    const int wn2 = wid * 32;
    f32x4 pa[4][2][2];
    {
        bf16x8 actx[4][2], bqs[4][2];
#pragma unroll
        for (int h = 0; h < 4; ++h)
#pragma unroll
            for (int ef = 0; ef < 2; ++ef) {
                int e = ef * 16 + lr;
                actx[h][ef] = *reinterpret_cast<const bf16x8*>(
                    &ctxT[h * 1024 + e * 32 + ((lk * 8) ^ ((e & 3) << 3))]);
            }
#pragma unroll
        for (int h = 0; h < 4; ++h)
#pragma unroll
            for (int nf = 0; nf < 2; ++nf)
                bqs[h][nf] = *reinterpret_cast<const bf16x8*>(
                    &qs[SWZ(wn2 + nf * 16 + lr, h * 32 + lk * 8)]);
#pragma unroll
        for (int h = 0; h < 4; ++h)
#pragma unroll
            for (int ef = 0; ef < 2; ++ef)
#pragma unroll
                for (int nf = 0; nf < 2; ++nf)
                    pa[h][ef][nf] = __builtin_amdgcn_mfma_f32_16x16x32_bf16(
                        actx[h][ef], bqs[h][nf], (f32x4){0.f, 0.f, 0.f, 0.f}, 0, 0, 0);
    }
    __syncthreads();
    // write ot[n][c] into qs region (row-major for phase-B A-operand)
#pragma unroll
    for (int h = 0; h < 4; ++h)
#pragma unroll
        for (int ef = 0; ef < 2; ++ef)
#pragma unroll
            for (int nf = 0; nf < 2; ++nf) {
                int n = wn2 + nf * 16 + lr;
                int cb = h * 32 + ef * 16 + lk * 4;
                u16x4 pk;
#pragma unroll
                for (int r = 0; r < 4; ++r) pk[r] = f2b(pa[h][ef][nf][r]);
                *reinterpret_cast<u16x4*>(&qs[SWZ(n, cb)]) = pk;
            }
    __syncthreads();

    // phase B: y[n][c] = sum_d ot[n][d] * w_out[d][c]
    const int wm = (wid >> 1) * 64, wn = (wid & 1) * 64;
    f32x4 acc[4][4];
#pragma unroll
    for (int mi = 0; mi < 4; ++mi)
#pragma unroll
        for (int ni = 0; ni < 4; ++ni) acc[mi][ni] = (f32x4){0.f, 0.f, 0.f, 0.f};
#pragma unroll
    for (int ks = 0; ks < 4; ++ks) {
        bf16x8 a[4], bb[4];
        const int kc = ks * 32 + lk * 8;
#pragma unroll
        for (int mi = 0; mi < 4; ++mi)
            a[mi] = *reinterpret_cast<const bf16x8*>(&qs[SWZ(wm + mi * 16 + lr, kc)]);
#pragma unroll
        for (int ni = 0; ni < 4; ++ni)
            bb[ni] = *reinterpret_cast<const bf16x8*>(&wB[SWZ(wn + ni * 16 + lr, kc)]);
#pragma unroll
        for (int mi = 0; mi < 4; ++mi)
#pragma unroll
            for (int ni = 0; ni < 4; ++ni)
                acc[mi][ni] = __builtin_amdgcn_mfma_f32_16x16x32_bf16(a[mi], bb[ni], acc[mi][ni], 0, 0, 0);
    }

    // fused LayerNorm. C layout: col c = wn+ni*16+lr, row = wm+mi*16+lk*4+r.
    float bias[4], lns[4];
#pragma unroll
    for (int ni = 0; ni < 4; ++ni) {
        int c = wn + ni * 16 + lr;
        bias[ni] = b_out[c];
        lns[ni]  = ln_scale[c];
    }
    float rs1[4][4], rs2[4][4];
#pragma unroll
    for (int mi = 0; mi < 4; ++mi)
#pragma unroll
        for (int r = 0; r < 4; ++r) {
            float s1 = 0.f, s2 = 0.f;
#pragma unroll
            for (int ni = 0; ni < 4; ++ni) {
                float v = acc[mi][ni][r] + bias[ni];
                s1 += v; s2 += v * v;
            }
            rs1[mi][r] = s1; rs2[mi][r] = s2;
        }
#pragma unroll
    for (int mask = 1; mask <= 8; mask <<= 1)
#pragma unroll
        for (int mi = 0; mi < 4; ++mi)
#pragma unroll
            for (int r = 0; r < 4; ++r) {
                rs1[mi][r] += __shfl_xor(rs1[mi][r], mask);
                rs2[mi][r] += __shfl_xor(rs2[mi][r], mask);
            }
    if (lr == 0) {
        const int hcol = wn >> 6;
#pragma unroll
        for (int mi = 0; mi < 4; ++mi)
#pragma unroll
            for (int r = 0; r < 4; ++r) {
                int row = wm + mi * 16 + lk * 4 + r;
                sums[row * 2 + hcol]       = rs1[mi][r];
                sums[256 + row * 2 + hcol] = rs2[mi][r];
            }
    }
    __syncthreads();
#pragma unroll
    for (int mi = 0; mi < 4; ++mi)
#pragma unroll
        for (int r = 0; r < 4; ++r) {
            int row = wm + mi * 16 + lk * 4 + r;
            float S1 = sums[row * 2] + sums[row * 2 + 1];
            float S2 = sums[256 + row * 2] + sums[256 + row * 2 + 1];
            float mu  = S1 * (1.0f / 128.0f);
            float var = S2 * (1.0f / 128.0f) - mu * mu;
            float rstd = rsqrtf(var + LN_EPS);
            float* op = out + (size_t)(row0 + row) * 128;
#pragma unroll
            for (int ni = 0; ni < 4; ++ni) {
                float v = acc[mi][ni][r] + bias[ni];
                op[wn + ni * 16 + lr] = (v - mu) * rstd * lns[ni];
            }
        }
}

// ---------------------------------------------------------------------------
extern "C" void kernel_launch(void* const* d_in, const int* in_sizes, int n_in,
                              void* d_out, int out_size, void* d_ws, size_t ws_size,
                              hipStream_t stream) {
    const float* x        = (const float*)d_in[0];
    const float* w_qkv    = (const float*)d_in[1];
    const float* w_out    = (const float*)d_in[2];
    const float* b_out    = (const float*)d_in[3];
    const float* ln_scale = (const float*)d_in[4];
    float* out = (float*)d_out;

    const size_t NTOT = (size_t)TOKENS * 128;   // 16.78M
    u16*   q_g    = (u16*)d_ws;                 // [n][128]
    u16*   ekT    = q_g + NTOT;                 // [128 f][TOKENS]
    u16*   vT     = ekT + NTOT;                 // [128 f][TOKENS]
    u16*   wqkvT  = vT + NTOT;                  // [384][128]
    u16*   woutT  = wqkvT + (size_t)F3 * CIN;   // [128][128]
    u16*   ctxg   = woutT + 128 * 128;          // [32][4096] bf16, pre-swizzled
    float* ctx_part  = (float*)(ctxg + 32 * 4096);      // [32][16][4096]
    float* ksum_part = ctx_part + (size_t)32 * 16 * 4096;   // [32][16][128]
    size_t need = (3 * NTOT + (size_t)F3 * CIN + 128 * 128 + 32 * 4096) * 2
                + ((size_t)32 * 16 * 4096 + 32 * 16 * 128) * 4;
    if (ws_size < need) return;

    const int lds_qkv = 2 * 16384 * sizeof(u16);             // 64 KB
    const int lds_ctx = 2 * 16384 * sizeof(u16);             // 64 KB
    const int lds_out = (4096 + 2 * 16384) * 2 + 512 * 4;    // 75776 B
    (void)hipFuncSetAttribute(reinterpret_cast<const void*>(k_qkv),
                              hipFuncAttributeMaxDynamicSharedMemorySize, lds_qkv);
    (void)hipFuncSetAttribute(reinterpret_cast<const void*>(k_ctx),
                              hipFuncAttributeMaxDynamicSharedMemorySize, lds_ctx);
    (void)hipFuncSetAttribute(reinterpret_cast<const void*>(k_out),
                              hipFuncAttributeMaxDynamicSharedMemorySize, lds_out);

    hipLaunchKernelGGL(k_prep_w, dim3(256), dim3(256), 0, stream, w_qkv, w_out, wqkvT, woutT);
    hipLaunchKernelGGL(k_qkv, dim3(1024), dim3(256), lds_qkv, stream, x, wqkvT, q_g, ekT, vT);
    hipLaunchKernelGGL(k_ctx, dim3(512), dim3(256), lds_ctx, stream, ekT, vT, ctx_part, ksum_part);
    hipLaunchKernelGGL(k_red, dim3(32), dim3(256), 0, stream, ctx_part, ksum_part, ctxg);
    hipLaunchKernelGGL(k_out, dim3(1024), dim3(256), lds_out, stream, q_g, ctxg,
                       woutT, b_out, ln_scale, out);
}

// Round 8
// 189.091 us; speedup vs baseline: 2.4135x; 1.0398x over previous
//
#include <hip/hip_runtime.h>
#include <hip/hip_bf16.h>
#include <math.h>

// Problem constants
#define TOKENS 131072      // 32*64*64 tokens
#define CIN    128         // input channels
#define F3     384         // 3*DIM qkv output channels
#define NTOK   4096        // tokens per batch (64*64)
#define LN_EPS 1e-5f

typedef unsigned short u16;
typedef u16   u16x4 __attribute__((ext_vector_type(4)));
typedef u16   u16x8 __attribute__((ext_vector_type(8)));
typedef __bf16 bf16x8 __attribute__((ext_vector_type(8)));
typedef float f32x4  __attribute__((ext_vector_type(4)));

static __device__ __forceinline__ u16 f2b(float f) {
    __bf16 h = (__bf16)f;                      // RNE hardware convert
    union { __bf16 hh; u16 uu; } c; c.hh = h; return c.uu;
}
static __device__ __forceinline__ float b2f(u16 u) {
    return __uint_as_float(((unsigned)u) << 16);
}

// LDS XOR swizzle for [rows][128 bf16] tiles read as ds_read_b128 down rows
// (T2, §6 G4): XOR 16B-granule index with (row&7).
#define SWZ(rr, cc) ((((rr) * 128) + (cc)) ^ (((rr) & 7) << 3))

// ---------------------------------------------------------------------------
// K0: wqkvT[f][k] = bf16(w_qkv[k][f]); w_outT[c][d] = bf16(w_out[d][c])
// ---------------------------------------------------------------------------
__global__ void k_prep_w(const float* __restrict__ wqkv, const float* __restrict__ wout,
                         u16* __restrict__ wqkvT, u16* __restrict__ woutT) {
    int t = blockIdx.x * 256 + threadIdx.x;     // 65536 total
    if (t < F3 * CIN) {
        int f = t >> 7, k = t & 127;
        wqkvT[t] = f2b(wqkv[(size_t)k * F3 + f]);
    } else {
        int j = t - F3 * CIN;                   // 16384
        int c = j >> 7, d = j & 127;
        woutT[j] = f2b(wout[(size_t)d * 128 + c]);
    }
}

// ---------------------------------------------------------------------------
// K1: qkv GEMM, 512 thr / 8 waves (wave = 32 tok x 64 f, acc 2x4).
// One block per 128-token tile; fc looped inside (x fetched once, B L2-hot).
// Epilogue: fc0 q row-major; fc1 exp(k) / fc2 v channel-major (u16x4 stores).
// ---------------------------------------------------------------------------
__global__ __launch_bounds__(512, 4) void k_qkv(
    const float* __restrict__ x, const u16* __restrict__ wT,
    u16* __restrict__ q_g, u16* __restrict__ ekT, u16* __restrict__ vT)
{
    extern __shared__ u16 lds[];
    u16* As = lds;            // 128x128 bf16, swizzled (32 KB)
    u16* Bs = lds + 16384;    // 128x128 bf16 (rows = f, cols = k), swizzled (32 KB)

    const int t = threadIdx.x;
    const long row0 = (long)blockIdx.x * 128;

    // stage A once: 128 rows x 32 float4 -> bf16, swizzled 8B writes
#pragma unroll
    for (int i = 0; i < 8; ++i) {
        int idx = i * 512 + t;
        int r = idx >> 5, c4 = idx & 31;
        float4 v = reinterpret_cast<const float4*>(x + (row0 + r) * CIN)[c4];
        u16x4 bq; bq[0] = f2b(v.x); bq[1] = f2b(v.y); bq[2] = f2b(v.z); bq[3] = f2b(v.w);
        *reinterpret_cast<u16x4*>(&As[SWZ(r, c4 * 4)]) = bq;
    }

    const int lane = t & 63, wid = t >> 6;
    const int wm = (wid >> 1) * 32, wn = (wid & 1) * 64;
    const int lr = lane & 15, lk = lane >> 4;

#pragma unroll
    for (int fc = 0; fc < 3; ++fc) {
        __syncthreads();   // fc0: A ready; fc>0: prior reads of Bs done
        // stage B chunk: 128 f-rows x 16 u16x8 units, swizzled 16B writes
#pragma unroll
        for (int i = 0; i < 4; ++i) {
            int idx = i * 512 + t;
            int f = idx >> 4, u = idx & 15;
            u16x8 wv = *reinterpret_cast<const u16x8*>(wT + (size_t)(fc * 128 + f) * 128 + u * 8);
            *reinterpret_cast<u16x8*>(&Bs[SWZ(f, u * 8)]) = wv;
        }
        __syncthreads();

        f32x4 acc[2][4];
#pragma unroll
        for (int mi = 0; mi < 2; ++mi)
#pragma unroll
            for (int ni = 0; ni < 4; ++ni)
                acc[mi][ni] = (f32x4){0.f, 0.f, 0.f, 0.f};

#pragma unroll
        for (int ks = 0; ks < 4; ++ks) {
            bf16x8 a[2], b[4];
            const int kc = ks * 32 + lk * 8;
#pragma unroll
            for (int mi = 0; mi < 2; ++mi)
                a[mi] = *reinterpret_cast<const bf16x8*>(&As[SWZ(wm + mi * 16 + lr, kc)]);
#pragma unroll
            for (int ni = 0; ni < 4; ++ni)
                b[ni] = *reinterpret_cast<const bf16x8*>(&Bs[SWZ(wn + ni * 16 + lr, kc)]);
#pragma unroll
            for (int mi = 0; mi < 2; ++mi)
#pragma unroll
                for (int ni = 0; ni < 4; ++ni)
                    acc[mi][ni] = __builtin_amdgcn_mfma_f32_16x16x32_bf16(a[mi], b[ni], acc[mi][ni], 0, 0, 0);
        }

        // C layout: col = lane&15, row = (lane>>4)*4 + reg (m89-verified)
        if (fc == 0) {
#pragma unroll
            for (int mi = 0; mi < 2; ++mi)
#pragma unroll
                for (int ni = 0; ni < 4; ++ni) {
                    const int col = wn + ni * 16 + lr;
                    const long rbase = row0 + wm + mi * 16 + lk * 4;
#pragma unroll
                    for (int r = 0; r < 4; ++r)
                        q_g[(rbase + r) * 128 + col] = f2b(acc[mi][ni][r]);
                }
        } else {
            u16* dstT = (fc == 1) ? ekT : vT;
            const bool ise = (fc == 1);
#pragma unroll
            for (int mi = 0; mi < 2; ++mi)
#pragma unroll
                for (int ni = 0; ni < 4; ++ni) {
                    const int col = wn + ni * 16 + lr;
                    const long rbase = row0 + wm + mi * 16 + lk * 4;
                    u16x4 pk;
#pragma unroll
                    for (int r = 0; r < 4; ++r) {
                        float vv = acc[mi][ni][r];
                        if (ise) vv = __expf(vv);
                        pk[r] = f2b(vv);
                    }
                    *reinterpret_cast<u16x4*>(dstT + (size_t)col * TOKENS + rbase) = pk;
                }
        }
    }
}

// ---------------------------------------------------------------------------
// K2: ctx_part[b,chunk,h,d,e] = sum_{n in 128-chunk} ekT[h*32+d][n]*vT[h*32+e][n]
//     ksum_part likewise. grid 1024 = 32 b x 32 chunks of 128 tokens.
//  4 waves, wave = head. LDS 64KB. No atomics; k_red reduces.
// ---------------------------------------------------------------------------
__global__ __launch_bounds__(256, 2) void k_ctx(
    const u16* __restrict__ ekT, const u16* __restrict__ vT,
    float* __restrict__ ctx_part, float* __restrict__ ksum_part)
{
    extern __shared__ u16 lds2[];
    u16* ek = lds2;           // [128 f][128 n] swizzled
    u16* vv = lds2 + 16384;

    const int t = threadIdx.x;
    const int b = blockIdx.x >> 5;
    const int chunk = blockIdx.x & 31;
    const long nb = (long)b * NTOK + chunk * 128;

    const int lane = t & 63, h = t >> 6;
    const int lr = lane & 15, lk = lane >> 4;
    const int unit = t & 15;
    const int fb = t >> 4;

#pragma unroll
    for (int p = 0; p < 8; ++p) {
        int f = fb * 8 + p;
        size_t goff = (size_t)f * TOKENS + nb + unit * 8;
        *reinterpret_cast<u16x8*>(&ek[SWZ(f, unit * 8)]) =
            *reinterpret_cast<const u16x8*>(ekT + goff);
        *reinterpret_cast<u16x8*>(&vv[SWZ(f, unit * 8)]) =
            *reinterpret_cast<const u16x8*>(vT + goff);
    }
    __syncthreads();

    f32x4 acc[2][2];
#pragma unroll
    for (int i = 0; i < 2; ++i)
#pragma unroll
        for (int j = 0; j < 2; ++j) acc[i][j] = (f32x4){0.f, 0.f, 0.f, 0.f};
    float ksr = 0.f;

#pragma unroll
    for (int ks = 0; ks < 4; ++ks) {
        const int kn = ks * 32 + lk * 8;
        bf16x8 a0 = *reinterpret_cast<const bf16x8*>(&ek[SWZ(h * 32 + lr, kn)]);
        bf16x8 a1 = *reinterpret_cast<const bf16x8*>(&ek[SWZ(h * 32 + 16 + lr, kn)]);
        bf16x8 b0 = *reinterpret_cast<const bf16x8*>(&vv[SWZ(h * 32 + lr, kn)]);
        bf16x8 b1 = *reinterpret_cast<const bf16x8*>(&vv[SWZ(h * 32 + 16 + lr, kn)]);
        acc[0][0] = __builtin_amdgcn_mfma_f32_16x16x32_bf16(a0, b0, acc[0][0], 0, 0, 0);
        acc[0][1] = __builtin_amdgcn_mfma_f32_16x16x32_bf16(a0, b1, acc[0][1], 0, 0, 0);
        acc[1][0] = __builtin_amdgcn_mfma_f32_16x16x32_bf16(a1, b0, acc[1][0], 0, 0, 0);
        acc[1][1] = __builtin_amdgcn_mfma_f32_16x16x32_bf16(a1, b1, acc[1][1], 0, 0, 0);
    }
    // ksum partial: lane d = lane&31, half = lane>>5 sums 64 n
    {
        const int d = lane & 31, half = lane >> 5;
        const int f = h * 32 + d;
#pragma unroll
        for (int j = 0; j < 8; ++j) {
            int n = half * 64 + j * 8;
            u16x8 e8 = *reinterpret_cast<const u16x8*>(&ek[SWZ(f, n)]);
#pragma unroll
            for (int i = 0; i < 8; ++i) ksr += b2f(e8[i]);
        }
    }

    ksr += __shfl_xor(ksr, 32);
    if (lane < 32) ksum_part[((size_t)b * 32 + chunk) * 128 + h * 32 + lane] = ksr;

    float* cp = ctx_part + ((size_t)b * 32 + chunk) * 4096 + h * 1024;
#pragma unroll
    for (int df = 0; df < 2; ++df)
#pragma unroll
        for (int ef = 0; ef < 2; ++ef)
#pragma unroll
            for (int r = 0; r < 4; ++r)
                cp[(df * 16 + lk * 4 + r) * 32 + ef * 16 + lr] = acc[df][ef][r];
}

// ---------------------------------------------------------------------------
// K2b: reduce 32 partials, normalize, emit pre-swizzled bf16 ctxT:
//      ctxg[b][h*1024 + e*32 + (d ^ ((e&3)<<3))] = ctx[h,d,e]/(ksum[h,d]*N)
// grid 256 = 32 b x 8 j-slices, 256 thr.
// ---------------------------------------------------------------------------
__global__ void k_red(const float* __restrict__ ctx_part, const float* __restrict__ ksum_part,
                      u16* __restrict__ ctxg) {
    __shared__ float ks[128];
    const int b = blockIdx.x >> 3, p = blockIdx.x & 7;
    const int t = threadIdx.x;
    const float* cp = ctx_part + (size_t)b * 32 * 4096;
    const float* kp = ksum_part + (size_t)b * 32 * 128;
    if (t < 128) {
        float s = 0.f;
#pragma unroll
        for (int c = 0; c < 32; ++c) s += kp[c * 128 + t];
        ks[t] = 1.0f / (s * 4096.0f);
    }
    __syncthreads();
#pragma unroll
    for (int i = 0; i < 2; ++i) {
        int j = p * 512 + i * 256 + t;    // = h*1024 + d*32 + e
        float s = 0.f;
#pragma unroll
        for (int c = 0; c < 32; ++c) s += cp[c * 4096 + j];
        int h = j >> 10, d = (j >> 5) & 31, e = j & 31;
        ctxg[(size_t)b * 4096 + h * 1024 + e * 32 + (d ^ ((e & 3) << 3))] = f2b(s * ks[j >> 5]);
    }
}

// ---------------------------------------------------------------------------
// K3: per 128 tokens, 512 thr / 8 waves: q-softmax -> out_tok = ctxT.qs
// (phase A: wave = (head-pair, 32-token block), 8 MFMA) -> y = ot @ w_outT
// (phase B: wave = 32 tok x 64 c, 32 MFMA) -> fused LayerNorm -> fp32 store.
// LDS 75776 B -> 2 blk/CU = 16 waves/CU.
// ---------------------------------------------------------------------------
__global__ __launch_bounds__(512, 4) void k_out(
    const u16* __restrict__ q_g, const u16* __restrict__ ctxg,
    const u16* __restrict__ woutT, const float* __restrict__ b_out, const float* __restrict__ ln_scale,
    float* __restrict__ out)
{
    extern __shared__ u16 sm16[];
    u16* ctxT = sm16;                    // [4][32 e][32 d] bf16, d-granule swizzled by e&3
    u16* qs   = sm16 + 4096;             // [128][128] bf16 SWZ (later overlaid with ot)
    u16* wB   = sm16 + 4096 + 16384;     // [128 c][128 d] bf16 SWZ
    float* sums = (float*)(sm16 + 4096 + 2 * 16384);  // s1[256], s2[256]

    const int t = threadIdx.x;
    const long row0 = (long)blockIdx.x * 128;
    const int b = (int)(row0 >> 12);
    const int lane = t & 63, wid = t >> 6;
    const int lr = lane & 15, lk = lane >> 4;

    // stage wB
#pragma unroll
    for (int i = 0; i < 4; ++i) {
        int j = i * 512 + t;
        int c = j >> 4, u = j & 15;
        *reinterpret_cast<u16x8*>(&wB[SWZ(c, u * 8)]) =
            *reinterpret_cast<const u16x8*>(woutT + (size_t)c * 128 + u * 8);
    }
    // ctxT: straight 8 KB copy (k_red already normalized + swizzled)
    *reinterpret_cast<u16x8*>(&ctxT[t * 8]) =
        *reinterpret_cast<const u16x8*>(ctxg + (size_t)b * 4096 + t * 8);
    // q softmax: thread owns one (row = t>>2, head = t&3)
    {
        const int row = t >> 2, hh = t & 3;
        const u16* qp = q_g + (size_t)(row0 + row) * 128 + hh * 32;
        float f[32];
#pragma unroll
        for (int g = 0; g < 4; ++g) {
            u16x8 v8 = *reinterpret_cast<const u16x8*>(qp + g * 8);
#pragma unroll
            for (int i = 0; i < 8; ++i) f[g * 8 + i] = b2f(v8[i]);
        }
        float m = f[0];
#pragma unroll
        for (int i = 1; i < 32; ++i) m = fmaxf(m, f[i]);
        float s = 0.f;
#pragma unroll
        for (int i = 0; i < 32; ++i) { f[i] = __expf(f[i] - m); s += f[i]; }
        float sc = 1.0f / (s * 5.65685424949238f);   // includes 1/sqrt(32)
#pragma unroll
        for (int g = 0; g < 4; ++g) {
            u16x8 o;
#pragma unroll
            for (int i = 0; i < 8; ++i) o[i] = f2b(f[g * 8 + i] * sc);
            *reinterpret_cast<u16x8*>(&qs[SWZ(row, hh * 32 + g * 8)]) = o;
        }
    }
    __syncthreads();

    // phase A: wave = (n-block nb, head-pair hp): D[e][n] = sum_d ctxT[e][d]*qs[n][h*32+d]
    const int nb = wid & 3, hp = wid >> 2;
    const int wn2 = nb * 32;
    f32x4 pa[2][2][2];
    {
        bf16x8 actx[2][2], bqs[2][2];
#pragma unroll
        for (int hi = 0; hi < 2; ++hi) {
            int h = hp * 2 + hi;
#pragma unroll
            for (int ef = 0; ef < 2; ++ef) {
                int e = ef * 16 + lr;
                actx[hi][ef] = *reinterpret_cast<const bf16x8*>(
                    &ctxT[h * 1024 + e * 32 + ((lk * 8) ^ ((e & 3) << 3))]);
            }
#pragma unroll
            for (int nf = 0; nf < 2; ++nf)
                bqs[hi][nf] = *reinterpret_cast<const bf16x8*>(
                    &qs[SWZ(wn2 + nf * 16 + lr, h * 32 + lk * 8)]);
        }
#pragma unroll
        for (int hi = 0; hi < 2; ++hi)
#pragma unroll
            for (int ef = 0; ef < 2; ++ef)
#pragma unroll
                for (int nf = 0; nf < 2; ++nf)
                    pa[hi][ef][nf] = __builtin_amdgcn_mfma_f32_16x16x32_bf16(
                        actx[hi][ef], bqs[hi][nf], (f32x4){0.f, 0.f, 0.f, 0.f}, 0, 0, 0);
    }
    __syncthreads();
    // write ot[n][c] into qs region (row-major for phase-B A-operand)
#pragma unroll
    for (int hi = 0; hi < 2; ++hi) {
        int h = hp * 2 + hi;
#pragma unroll
        for (int ef = 0; ef < 2; ++ef)
#pragma unroll
            for (int nf = 0; nf < 2; ++nf) {
                int n = wn2 + nf * 16 + lr;
                int cb = h * 32 + ef * 16 + lk * 4;
                u16x4 pk;
#pragma unroll
                for (int r = 0; r < 4; ++r) pk[r] = f2b(pa[hi][ef][nf][r]);
                *reinterpret_cast<u16x4*>(&qs[SWZ(n, cb)]) = pk;
            }
    }
    __syncthreads();

    // phase B: y[n][c] = sum_d ot[n][d] * w_out[d][c]; wave = 32 tok x 64 c
    const int wm = (wid >> 1) * 32, wn = (wid & 1) * 64;
    f32x4 acc[2][4];
#pragma unroll
    for (int mi = 0; mi < 2; ++mi)
#pragma unroll
        for (int ni = 0; ni < 4; ++ni) acc[mi][ni] = (f32x4){0.f, 0.f, 0.f, 0.f};
#pragma unroll
    for (int ks = 0; ks < 4; ++ks) {
        bf16x8 a[2], bb[4];
        const int kc = ks * 32 + lk * 8;
#pragma unroll
        for (int mi = 0; mi < 2; ++mi)
            a[mi] = *reinterpret_cast<const bf16x8*>(&qs[SWZ(wm + mi * 16 + lr, kc)]);
#pragma unroll
        for (int ni = 0; ni < 4; ++ni)
            bb[ni] = *reinterpret_cast<const bf16x8*>(&wB[SWZ(wn + ni * 16 + lr, kc)]);
#pragma unroll
        for (int mi = 0; mi < 2; ++mi)
#pragma unroll
            for (int ni = 0; ni < 4; ++ni)
                acc[mi][ni] = __builtin_amdgcn_mfma_f32_16x16x32_bf16(a[mi], bb[ni], acc[mi][ni], 0, 0, 0);
    }

    // fused LayerNorm. C layout: col c = wn+ni*16+lr, row = wm+mi*16+lk*4+r.
    float bias[4], lns[4];
#pragma unroll
    for (int ni = 0; ni < 4; ++ni) {
        int c = wn + ni * 16 + lr;
        bias[ni] = b_out[c];
        lns[ni]  = ln_scale[c];
    }
    float rs1[2][4], rs2[2][4];
#pragma unroll
    for (int mi = 0; mi < 2; ++mi)
#pragma unroll
        for (int r = 0; r < 4; ++r) {
            float s1 = 0.f, s2 = 0.f;
#pragma unroll
            for (int ni = 0; ni < 4; ++ni) {
                float v = acc[mi][ni][r] + bias[ni];
                s1 += v; s2 += v * v;
            }
            rs1[mi][r] = s1; rs2[mi][r] = s2;
        }
#pragma unroll
    for (int mask = 1; mask <= 8; mask <<= 1)
#pragma unroll
        for (int mi = 0; mi < 2; ++mi)
#pragma unroll
            for (int r = 0; r < 4; ++r) {
                rs1[mi][r] += __shfl_xor(rs1[mi][r], mask);
                rs2[mi][r] += __shfl_xor(rs2[mi][r], mask);
            }
    if (lr == 0) {
        const int hcol = wn >> 6;
#pragma unroll
        for (int mi = 0; mi < 2; ++mi)
#pragma unroll
            for (int r = 0; r < 4; ++r) {
                int row = wm + mi * 16 + lk * 4 + r;
                sums[row * 2 + hcol]       = rs1[mi][r];
                sums[256 + row * 2 + hcol] = rs2[mi][r];
            }
    }
    __syncthreads();
#pragma unroll
    for (int mi = 0; mi < 2; ++mi)
#pragma unroll
        for (int r = 0; r < 4; ++r) {
            int row = wm + mi * 16 + lk * 4 + r;
            float S1 = sums[row * 2] + sums[row * 2 + 1];
            float S2 = sums[256 + row * 2] + sums[256 + row * 2 + 1];
            float mu  = S1 * (1.0f / 128.0f);
            float var = S2 * (1.0f / 128.0f) - mu * mu;
            float rstd = rsqrtf(var + LN_EPS);
            float* op = out + (size_t)(row0 + row) * 128;
#pragma unroll
            for (int ni = 0; ni < 4; ++ni) {
                float v = acc[mi][ni][r] + bias[ni];
                op[wn + ni * 16 + lr] = (v - mu) * rstd * lns[ni];
            }
        }
}

// ---------------------------------------------------------------------------
extern "C" void kernel_launch(void* const* d_in, const int* in_sizes, int n_in,
                              void* d_out, int out_size, void* d_ws, size_t ws_size,
                              hipStream_t stream) {
    const float* x        = (const float*)d_in[0];
    const float* w_qkv    = (const float*)d_in[1];
    const float* w_out    = (const float*)d_in[2];
    const float* b_out    = (const float*)d_in[3];
    const float* ln_scale = (const float*)d_in[4];
    float* out = (float*)d_out;

    const size_t NTOT = (size_t)TOKENS * 128;   // 16.78M
    u16*   q_g    = (u16*)d_ws;                 // [n][128]
    u16*   ekT    = q_g + NTOT;                 // [128 f][TOKENS]
    u16*   vT     = ekT + NTOT;                 // [128 f][TOKENS]
    u16*   wqkvT  = vT + NTOT;                  // [384][128]
    u16*   woutT  = wqkvT + (size_t)F3 * CIN;   // [128][128]
    u16*   ctxg   = woutT + 128 * 128;          // [32][4096] bf16, pre-swizzled
    float* ctx_part  = (float*)(ctxg + 32 * 4096);          // [32][32][4096]
    float* ksum_part = ctx_part + (size_t)32 * 32 * 4096;   // [32][32][128]
    size_t need = (3 * NTOT + (size_t)F3 * CIN + 128 * 128 + 32 * 4096) * 2
                + ((size_t)32 * 32 * 4096 + (size_t)32 * 32 * 128) * 4;
    if (ws_size < need) return;

    const int lds_qkv = 2 * 16384 * sizeof(u16);             // 64 KB
    const int lds_ctx = 2 * 16384 * sizeof(u16);             // 64 KB
    const int lds_out = (4096 + 2 * 16384) * 2 + 512 * 4;    // 75776 B
    (void)hipFuncSetAttribute(reinterpret_cast<const void*>(k_qkv),
                              hipFuncAttributeMaxDynamicSharedMemorySize, lds_qkv);
    (void)hipFuncSetAttribute(reinterpret_cast<const void*>(k_ctx),
                              hipFuncAttributeMaxDynamicSharedMemorySize, lds_ctx);
    (void)hipFuncSetAttribute(reinterpret_cast<const void*>(k_out),
                              hipFuncAttributeMaxDynamicSharedMemorySize, lds_out);

    hipLaunchKernelGGL(k_prep_w, dim3(256), dim3(256), 0, stream, w_qkv, w_out, wqkvT, woutT);
    hipLaunchKernelGGL(k_qkv, dim3(1024), dim3(512), lds_qkv, stream, x, wqkvT, q_g, ekT, vT);
    hipLaunchKernelGGL(k_ctx, dim3(1024), dim3(256), lds_ctx, stream, ekT, vT, ctx_part, ksum_part);
    hipLaunchKernelGGL(k_red, dim3(256), dim3(256), 0, stream, ctx_part, ksum_part, ctxg);
    hipLaunchKernelGGL(k_out, dim3(1024), dim3(512), lds_out, stream, q_g, ctxg,
                       woutT, b_out, ln_scale, out);
}

// Round 9
// 166.788 us; speedup vs baseline: 2.7363x; 1.1337x over previous
//
#include <hip/hip_runtime.h>
#include <hip/hip_bf16.h>
#include <math.h>

// Problem constants
#define TOKENS 131072      // 32*64*64 tokens
#define CIN    128         // input channels
#define F3     384         // 3*DIM qkv output channels
#define NTOK   4096        // tokens per batch (64*64)
#define LN_EPS 1e-5f

typedef unsigned short u16;
typedef u16   u16x4 __attribute__((ext_vector_type(4)));
typedef u16   u16x8 __attribute__((ext_vector_type(8)));
typedef __bf16 bf16x8 __attribute__((ext_vector_type(8)));
typedef float f32x4  __attribute__((ext_vector_type(4)));

static __device__ __forceinline__ u16 f2b(float f) {
    __bf16 h = (__bf16)f;                      // RNE hardware convert
    union { __bf16 hh; u16 uu; } c; c.hh = h; return c.uu;
}
static __device__ __forceinline__ float b2f(u16 u) {
    return __uint_as_float(((unsigned)u) << 16);
}

// LDS XOR swizzle for [rows][128 bf16] tiles read as ds_read_b128 down rows
// (T2, §6 G4): XOR 16B-granule index with (row&7).
#define SWZ(rr, cc) ((((rr) * 128) + (cc)) ^ (((rr) & 7) << 3))

// ---------------------------------------------------------------------------
// K0: wqkvT[f][k] = bf16(w_qkv[k][f]); w_outT[c][d] = bf16(w_out[d][c])
// ---------------------------------------------------------------------------
__global__ void k_prep_w(const float* __restrict__ wqkv, const float* __restrict__ wout,
                         u16* __restrict__ wqkvT, u16* __restrict__ woutT) {
    int t = blockIdx.x * 256 + threadIdx.x;     // 65536 total
    if (t < F3 * CIN) {
        int f = t >> 7, k = t & 127;
        wqkvT[t] = f2b(wqkv[(size_t)k * F3 + f]);
    } else {
        int j = t - F3 * CIN;                   // 16384
        int c = j >> 7, d = j & 127;
        woutT[j] = f2b(wout[(size_t)d * 128 + c]);
    }
}

// ---------------------------------------------------------------------------
// K1: FUSED qkv GEMM + ctx reduction. 512 thr / 8 waves.
// Per 128-token block: stage A (x->bf16); fc loop {stage B(fc), 8 MFMA/wave}:
//   fc0: q -> q_g row-major (global)
//   fc1: exp(k) -> E LDS [f][n]          (never touches HBM)
//   fc2: v -> V LDS [f][n], overlaying As (barrier first)
// then ctx phase: wave (h,dh) computes ctx_part[d16,e32] = E.V^T over 128 n
// (8 MFMA) + ksum from E. Partials stored per block; k_red reduces.
// LDS 96 KB -> 1 block/CU.
// ---------------------------------------------------------------------------
__global__ __launch_bounds__(512, 2) void k_qkvc(
    const float* __restrict__ x, const u16* __restrict__ wT,
    u16* __restrict__ q_g, float* __restrict__ ctx_part, float* __restrict__ ksum_part)
{
    extern __shared__ u16 lds[];
    u16* As = lds;            // [128 tok][128 k] swizzled; later V [128 f][128 n]
    u16* Bs = lds + 16384;    // [128 f][128 k] swizzled, per fc
    u16* E  = lds + 32768;    // [128 f][128 n] swizzled = exp(k)

    const int t = threadIdx.x;
    const long row0 = (long)blockIdx.x * 128;

    // stage A once: 128 rows x 32 float4 -> bf16, swizzled 8B writes
#pragma unroll
    for (int i = 0; i < 8; ++i) {
        int idx = i * 512 + t;
        int r = idx >> 5, c4 = idx & 31;
        float4 v = reinterpret_cast<const float4*>(x + (row0 + r) * CIN)[c4];
        u16x4 bq; bq[0] = f2b(v.x); bq[1] = f2b(v.y); bq[2] = f2b(v.z); bq[3] = f2b(v.w);
        *reinterpret_cast<u16x4*>(&As[SWZ(r, c4 * 4)]) = bq;
    }

    const int lane = t & 63, wid = t >> 6;
    const int wm = (wid >> 1) * 32, wn = (wid & 1) * 64;
    const int lr = lane & 15, lk = lane >> 4;

#pragma unroll
    for (int fc = 0; fc < 3; ++fc) {
        __syncthreads();   // fc0: A ready; fc>0: prior reads of Bs done
        // stage B chunk: 128 f-rows x 16 u16x8 units, swizzled 16B writes
#pragma unroll
        for (int i = 0; i < 4; ++i) {
            int idx = i * 512 + t;
            int f = idx >> 4, u = idx & 15;
            u16x8 wv = *reinterpret_cast<const u16x8*>(wT + (size_t)(fc * 128 + f) * 128 + u * 8);
            *reinterpret_cast<u16x8*>(&Bs[SWZ(f, u * 8)]) = wv;
        }
        __syncthreads();

        f32x4 acc[2][4];
#pragma unroll
        for (int mi = 0; mi < 2; ++mi)
#pragma unroll
            for (int ni = 0; ni < 4; ++ni)
                acc[mi][ni] = (f32x4){0.f, 0.f, 0.f, 0.f};

#pragma unroll
        for (int ks = 0; ks < 4; ++ks) {
            bf16x8 a[2], b[4];
            const int kc = ks * 32 + lk * 8;
#pragma unroll
            for (int mi = 0; mi < 2; ++mi)
                a[mi] = *reinterpret_cast<const bf16x8*>(&As[SWZ(wm + mi * 16 + lr, kc)]);
#pragma unroll
            for (int ni = 0; ni < 4; ++ni)
                b[ni] = *reinterpret_cast<const bf16x8*>(&Bs[SWZ(wn + ni * 16 + lr, kc)]);
#pragma unroll
            for (int mi = 0; mi < 2; ++mi)
#pragma unroll
                for (int ni = 0; ni < 4; ++ni)
                    acc[mi][ni] = __builtin_amdgcn_mfma_f32_16x16x32_bf16(a[mi], b[ni], acc[mi][ni], 0, 0, 0);
        }

        // C layout: col = lane&15, row = (lane>>4)*4 + reg (m89-verified)
        if (fc == 0) {
#pragma unroll
            for (int mi = 0; mi < 2; ++mi)
#pragma unroll
                for (int ni = 0; ni < 4; ++ni) {
                    const int col = wn + ni * 16 + lr;
                    const long rbase = row0 + wm + mi * 16 + lk * 4;
#pragma unroll
                    for (int r = 0; r < 4; ++r)
                        q_g[(rbase + r) * 128 + col] = f2b(acc[mi][ni][r]);
                }
        } else if (fc == 1) {
            // exp(k) -> E[f][n] (u16x4 8B writes, 2-way-bank at worst)
#pragma unroll
            for (int mi = 0; mi < 2; ++mi)
#pragma unroll
                for (int ni = 0; ni < 4; ++ni) {
                    const int f = wn + ni * 16 + lr;
                    const int nbase = wm + mi * 16 + lk * 4;
                    u16x4 pk;
#pragma unroll
                    for (int r = 0; r < 4; ++r) pk[r] = f2b(__expf(acc[mi][ni][r]));
                    *reinterpret_cast<u16x4*>(&E[SWZ(f, nbase)]) = pk;
                }
        } else {
            __syncthreads();   // all waves done reading As before overlaying V
#pragma unroll
            for (int mi = 0; mi < 2; ++mi)
#pragma unroll
                for (int ni = 0; ni < 4; ++ni) {
                    const int f = wn + ni * 16 + lr;
                    const int nbase = wm + mi * 16 + lk * 4;
                    u16x4 pk;
#pragma unroll
                    for (int r = 0; r < 4; ++r) pk[r] = f2b(acc[mi][ni][r]);
                    *reinterpret_cast<u16x4*>(&As[SWZ(f, nbase)]) = pk;
                }
        }
    }
    __syncthreads();   // E and V(As) visible to all waves

    // ctx phase: wave = (h = wid>>1, dh = wid&1); d = dh*16+lk*4+r, e = ef*16+lr
    {
        const int h = wid >> 1, dh = wid & 1;
        f32x4 cacc[2];
        cacc[0] = (f32x4){0.f, 0.f, 0.f, 0.f};
        cacc[1] = (f32x4){0.f, 0.f, 0.f, 0.f};
#pragma unroll
        for (int ks = 0; ks < 4; ++ks) {
            const int kn = ks * 32 + lk * 8;
            bf16x8 ae = *reinterpret_cast<const bf16x8*>(&E[SWZ(h * 32 + dh * 16 + lr, kn)]);
            bf16x8 b0 = *reinterpret_cast<const bf16x8*>(&As[SWZ(h * 32 + lr, kn)]);
            bf16x8 b1 = *reinterpret_cast<const bf16x8*>(&As[SWZ(h * 32 + 16 + lr, kn)]);
            cacc[0] = __builtin_amdgcn_mfma_f32_16x16x32_bf16(ae, b0, cacc[0], 0, 0, 0);
            cacc[1] = __builtin_amdgcn_mfma_f32_16x16x32_bf16(ae, b1, cacc[1], 0, 0, 0);
        }
        float* cp = ctx_part + (size_t)blockIdx.x * 4096 + h * 1024;
#pragma unroll
        for (int ef = 0; ef < 2; ++ef)
#pragma unroll
            for (int r = 0; r < 4; ++r)
                cp[(dh * 16 + lk * 4 + r) * 32 + ef * 16 + lr] = cacc[ef][r];
    }
    // ksum: 4 threads per f-row, each sums 32 n, pair-shuffle reduce
    {
        const int rowf = t >> 2, q4 = t & 3;
        float s = 0.f;
#pragma unroll
        for (int j = 0; j < 4; ++j) {
            u16x8 e8 = *reinterpret_cast<const u16x8*>(&E[SWZ(rowf, q4 * 32 + j * 8)]);
#pragma unroll
            for (int i = 0; i < 8; ++i) s += b2f(e8[i]);
        }
        s += __shfl_xor(s, 1);
        s += __shfl_xor(s, 2);
        if ((t & 3) == 0) ksum_part[(size_t)blockIdx.x * 128 + rowf] = s;
    }
}

// ---------------------------------------------------------------------------
// K2b: reduce 32 partials, normalize, emit pre-swizzled bf16 ctxT:
//      ctxg[b][h*1024 + e*32 + (d ^ ((e&3)<<3))] = ctx[h,d,e]/(ksum[h,d]*N)
// grid 256 = 32 b x 8 j-slices, 256 thr.
// ---------------------------------------------------------------------------
__global__ void k_red(const float* __restrict__ ctx_part, const float* __restrict__ ksum_part,
                      u16* __restrict__ ctxg) {
    __shared__ float ks[128];
    const int b = blockIdx.x >> 3, p = blockIdx.x & 7;
    const int t = threadIdx.x;
    const float* cp = ctx_part + (size_t)b * 32 * 4096;
    const float* kp = ksum_part + (size_t)b * 32 * 128;
    if (t < 128) {
        float s = 0.f;
#pragma unroll
        for (int c = 0; c < 32; ++c) s += kp[c * 128 + t];
        ks[t] = 1.0f / (s * 4096.0f);
    }
    __syncthreads();
#pragma unroll
    for (int i = 0; i < 2; ++i) {
        int j = p * 512 + i * 256 + t;    // = h*1024 + d*32 + e
        float s = 0.f;
#pragma unroll
        for (int c = 0; c < 32; ++c) s += cp[c * 4096 + j];
        int h = j >> 10, d = (j >> 5) & 31, e = j & 31;
        ctxg[(size_t)b * 4096 + h * 1024 + e * 32 + (d ^ ((e & 3) << 3))] = f2b(s * ks[j >> 5]);
    }
}

// ---------------------------------------------------------------------------
// K3: per 128 tokens, 512 thr / 8 waves: q-softmax -> out_tok = ctxT.qs
// (phase A: wave = (head-pair, 32-token block), 8 MFMA) -> y = ot @ w_outT
// (phase B: wave = 32 tok x 64 c, 32 MFMA) -> fused LayerNorm -> fp32 store.
// LDS 75776 B -> 2 blk/CU = 16 waves/CU.
// ---------------------------------------------------------------------------
__global__ __launch_bounds__(512, 4) void k_out(
    const u16* __restrict__ q_g, const u16* __restrict__ ctxg,
    const u16* __restrict__ woutT, const float* __restrict__ b_out, const float* __restrict__ ln_scale,
    float* __restrict__ out)
{
    extern __shared__ u16 sm16[];
    u16* ctxT = sm16;                    // [4][32 e][32 d] bf16, d-granule swizzled by e&3
    u16* qs   = sm16 + 4096;             // [128][128] bf16 SWZ (later overlaid with ot)
    u16* wB   = sm16 + 4096 + 16384;     // [128 c][128 d] bf16 SWZ
    float* sums = (float*)(sm16 + 4096 + 2 * 16384);  // s1[256], s2[256]

    const int t = threadIdx.x;
    const long row0 = (long)blockIdx.x * 128;
    const int b = (int)(row0 >> 12);
    const int lane = t & 63, wid = t >> 6;
    const int lr = lane & 15, lk = lane >> 4;

    // stage wB
#pragma unroll
    for (int i = 0; i < 4; ++i) {
        int j = i * 512 + t;
        int c = j >> 4, u = j & 15;
        *reinterpret_cast<u16x8*>(&wB[SWZ(c, u * 8)]) =
            *reinterpret_cast<const u16x8*>(woutT + (size_t)c * 128 + u * 8);
    }
    // ctxT: straight 8 KB copy (k_red already normalized + swizzled)
    *reinterpret_cast<u16x8*>(&ctxT[t * 8]) =
        *reinterpret_cast<const u16x8*>(ctxg + (size_t)b * 4096 + t * 8);
    // q softmax: thread owns one (row = t>>2, head = t&3)
    {
        const int row = t >> 2, hh = t & 3;
        const u16* qp = q_g + (size_t)(row0 + row) * 128 + hh * 32;
        float f[32];
#pragma unroll
        for (int g = 0; g < 4; ++g) {
            u16x8 v8 = *reinterpret_cast<const u16x8*>(qp + g * 8);
#pragma unroll
            for (int i = 0; i < 8; ++i) f[g * 8 + i] = b2f(v8[i]);
        }
        float m = f[0];
#pragma unroll
        for (int i = 1; i < 32; ++i) m = fmaxf(m, f[i]);
        float s = 0.f;
#pragma unroll
        for (int i = 0; i < 32; ++i) { f[i] = __expf(f[i] - m); s += f[i]; }
        float sc = 1.0f / (s * 5.65685424949238f);   // includes 1/sqrt(32)
#pragma unroll
        for (int g = 0; g < 4; ++g) {
            u16x8 o;
#pragma unroll
            for (int i = 0; i < 8; ++i) o[i] = f2b(f[g * 8 + i] * sc);
            *reinterpret_cast<u16x8*>(&qs[SWZ(row, hh * 32 + g * 8)]) = o;
        }
    }
    __syncthreads();

    // phase A: wave = (n-block nb, head-pair hp): D[e][n] = sum_d ctxT[e][d]*qs[n][h*32+d]
    const int nb = wid & 3, hp = wid >> 2;
    const int wn2 = nb * 32;
    f32x4 pa[2][2][2];
    {
        bf16x8 actx[2][2], bqs[2][2];
#pragma unroll
        for (int hi = 0; hi < 2; ++hi) {
            int h = hp * 2 + hi;
#pragma unroll
            for (int ef = 0; ef < 2; ++ef) {
                int e = ef * 16 + lr;
                actx[hi][ef] = *reinterpret_cast<const bf16x8*>(
                    &ctxT[h * 1024 + e * 32 + ((lk * 8) ^ ((e & 3) << 3))]);
            }
#pragma unroll
            for (int nf = 0; nf < 2; ++nf)
                bqs[hi][nf] = *reinterpret_cast<const bf16x8*>(
                    &qs[SWZ(wn2 + nf * 16 + lr, h * 32 + lk * 8)]);
        }
#pragma unroll
        for (int hi = 0; hi < 2; ++hi)
#pragma unroll
            for (int ef = 0; ef < 2; ++ef)
#pragma unroll
                for (int nf = 0; nf < 2; ++nf)
                    pa[hi][ef][nf] = __builtin_amdgcn_mfma_f32_16x16x32_bf16(
                        actx[hi][ef], bqs[hi][nf], (f32x4){0.f, 0.f, 0.f, 0.f}, 0, 0, 0);
    }
    __syncthreads();
    // write ot[n][c] into qs region (row-major for phase-B A-operand)
#pragma unroll
    for (int hi = 0; hi < 2; ++hi) {
        int h = hp * 2 + hi;
#pragma unroll
        for (int ef = 0; ef < 2; ++ef)
#pragma unroll
            for (int nf = 0; nf < 2; ++nf) {
                int n = wn2 + nf * 16 + lr;
                int cb = h * 32 + ef * 16 + lk * 4;
                u16x4 pk;
#pragma unroll
                for (int r = 0; r < 4; ++r) pk[r] = f2b(pa[hi][ef][nf][r]);
                *reinterpret_cast<u16x4*>(&qs[SWZ(n, cb)]) = pk;
            }
    }
    __syncthreads();

    // phase B: y[n][c] = sum_d ot[n][d] * w_out[d][c]; wave = 32 tok x 64 c
    const int wm = (wid >> 1) * 32, wn = (wid & 1) * 64;
    f32x4 acc[2][4];
#pragma unroll
    for (int mi = 0; mi < 2; ++mi)
#pragma unroll
        for (int ni = 0; ni < 4; ++ni) acc[mi][ni] = (f32x4){0.f, 0.f, 0.f, 0.f};
#pragma unroll
    for (int ks = 0; ks < 4; ++ks) {
        bf16x8 a[2], bb[4];
        const int kc = ks * 32 + lk * 8;
#pragma unroll
        for (int mi = 0; mi < 2; ++mi)
            a[mi] = *reinterpret_cast<const bf16x8*>(&qs[SWZ(wm + mi * 16 + lr, kc)]);
#pragma unroll
        for (int ni = 0; ni < 4; ++ni)
            bb[ni] = *reinterpret_cast<const bf16x8*>(&wB[SWZ(wn + ni * 16 + lr, kc)]);
#pragma unroll
        for (int mi = 0; mi < 2; ++mi)
#pragma unroll
            for (int ni = 0; ni < 4; ++ni)
                acc[mi][ni] = __builtin_amdgcn_mfma_f32_16x16x32_bf16(a[mi], bb[ni], acc[mi][ni], 0, 0, 0);
    }

    // fused LayerNorm. C layout: col c = wn+ni*16+lr, row = wm+mi*16+lk*4+r.
    float bias[4], lns[4];
#pragma unroll
    for (int ni = 0; ni < 4; ++ni) {
        int c = wn + ni * 16 + lr;
        bias[ni] = b_out[c];
        lns[ni]  = ln_scale[c];
    }
    float rs1[2][4], rs2[2][4];
#pragma unroll
    for (int mi = 0; mi < 2; ++mi)
#pragma unroll
        for (int r = 0; r < 4; ++r) {
            float s1 = 0.f, s2 = 0.f;
#pragma unroll
            for (int ni = 0; ni < 4; ++ni) {
                float v = acc[mi][ni][r] + bias[ni];
                s1 += v; s2 += v * v;
            }
            rs1[mi][r] = s1; rs2[mi][r] = s2;
        }
#pragma unroll
    for (int mask = 1; mask <= 8; mask <<= 1)
#pragma unroll
        for (int mi = 0; mi < 2; ++mi)
#pragma unroll
            for (int r = 0; r < 4; ++r) {
                rs1[mi][r] += __shfl_xor(rs1[mi][r], mask);
                rs2[mi][r] += __shfl_xor(rs2[mi][r], mask);
            }
    if (lr == 0) {
        const int hcol = wn >> 6;
#pragma unroll
        for (int mi = 0; mi < 2; ++mi)
#pragma unroll
            for (int r = 0; r < 4; ++r) {
                int row = wm + mi * 16 + lk * 4 + r;
                sums[row * 2 + hcol]       = rs1[mi][r];
                sums[256 + row * 2 + hcol] = rs2[mi][r];
            }
    }
    __syncthreads();
#pragma unroll
    for (int mi = 0; mi < 2; ++mi)
#pragma unroll
        for (int r = 0; r < 4; ++r) {
            int row = wm + mi * 16 + lk * 4 + r;
            float S1 = sums[row * 2] + sums[row * 2 + 1];
            float S2 = sums[256 + row * 2] + sums[256 + row * 2 + 1];
            float mu  = S1 * (1.0f / 128.0f);
            float var = S2 * (1.0f / 128.0f) - mu * mu;
            float rstd = rsqrtf(var + LN_EPS);
            float* op = out + (size_t)(row0 + row) * 128;
#pragma unroll
            for (int ni = 0; ni < 4; ++ni) {
                float v = acc[mi][ni][r] + bias[ni];
                op[wn + ni * 16 + lr] = (v - mu) * rstd * lns[ni];
            }
        }
}

// ---------------------------------------------------------------------------
extern "C" void kernel_launch(void* const* d_in, const int* in_sizes, int n_in,
                              void* d_out, int out_size, void* d_ws, size_t ws_size,
                              hipStream_t stream) {
    const float* x        = (const float*)d_in[0];
    const float* w_qkv    = (const float*)d_in[1];
    const float* w_out    = (const float*)d_in[2];
    const float* b_out    = (const float*)d_in[3];
    const float* ln_scale = (const float*)d_in[4];
    float* out = (float*)d_out;

    const size_t NTOT = (size_t)TOKENS * 128;   // 16.78M
    u16*   q_g    = (u16*)d_ws;                 // [n][128]
    u16*   wqkvT  = q_g + NTOT;                 // [384][128]
    u16*   woutT  = wqkvT + (size_t)F3 * CIN;   // [128][128]
    u16*   ctxg   = woutT + 128 * 128;          // [32][4096] bf16, pre-swizzled
    float* ctx_part  = (float*)(ctxg + 32 * 4096);          // [32][32][4096]
    float* ksum_part = ctx_part + (size_t)32 * 32 * 4096;   // [32][32][128]
    size_t need = (NTOT + (size_t)F3 * CIN + 128 * 128 + 32 * 4096) * 2
                + ((size_t)32 * 32 * 4096 + (size_t)32 * 32 * 128) * 4;
    if (ws_size < need) return;

    const int lds_qkvc = 3 * 16384 * sizeof(u16);            // 96 KB
    const int lds_out  = (4096 + 2 * 16384) * 2 + 512 * 4;   // 75776 B
    (void)hipFuncSetAttribute(reinterpret_cast<const void*>(k_qkvc),
                              hipFuncAttributeMaxDynamicSharedMemorySize, lds_qkvc);
    (void)hipFuncSetAttribute(reinterpret_cast<const void*>(k_out),
                              hipFuncAttributeMaxDynamicSharedMemorySize, lds_out);

    hipLaunchKernelGGL(k_prep_w, dim3(256), dim3(256), 0, stream, w_qkv, w_out, wqkvT, woutT);
    hipLaunchKernelGGL(k_qkvc, dim3(1024), dim3(512), lds_qkvc, stream, x, wqkvT,
                       q_g, ctx_part, ksum_part);
    hipLaunchKernelGGL(k_red, dim3(256), dim3(256), 0, stream, ctx_part, ksum_part, ctxg);
    hipLaunchKernelGGL(k_out, dim3(1024), dim3(512), lds_out, stream, q_g, ctxg,
                       woutT, b_out, ln_scale, out);
}